// Round 4
// baseline (238.512 us; speedup 1.0000x reference)
//
#include <hip/hip_runtime.h>
#include <cstddef>

namespace {

constexpr int B=4, V=6, C=256, HWS=1024, S=6144, NH=4, HD=64, VC=1536;

typedef short short8  __attribute__((ext_vector_type(8)));
typedef short short4v __attribute__((ext_vector_type(4)));
typedef float f32x4   __attribute__((ext_vector_type(4)));

__device__ inline short f2bf(float f){
  union{float f; unsigned u;} v; v.f=f;
  unsigned r = v.u + 0x7fffu + ((v.u>>16)&1u);   // RNE
  return (short)(r>>16);
}

// ---------------------------------------------------------------------------
// 64x64 transpose-cast tile: fp32 in[R][Cc] -> bf16 out[Cc][R].
// ---------------------------------------------------------------------------
__device__ inline void tr_tile(const float* in, int inRow, short* out, int outRow,
                               int r0, int c0, short* T /*64*72*/, int t){
  {
    const int rr=t>>2, cc=(t&3)*16;
    const float* p = in + (size_t)(r0+rr)*inRow + c0 + cc;
    short tmp[16];
    #pragma unroll
    for(int j=0;j<4;j++){
      const float4 f=*(const float4*)(p+j*4);
      tmp[j*4+0]=f2bf(f.x); tmp[j*4+1]=f2bf(f.y);
      tmp[j*4+2]=f2bf(f.z); tmp[j*4+3]=f2bf(f.w);
    }
    *(short8*)&T[rr*72+cc]   = *(short8*)&tmp[0];
    *(short8*)&T[rr*72+cc+8] = *(short8*)&tmp[8];
  }
  __syncthreads();
  {
    const int cc=t>>2, rr0=(t&3)*16;
    short tmp[16];
    #pragma unroll
    for(int j=0;j<16;j++) tmp[j]=T[(rr0+j)*72+cc];
    short* o = out + (size_t)(c0+cc)*outRow + r0 + rr0;
    *(short8*)o     = *(short8*)&tmp[0];
    *(short8*)(o+8) = *(short8*)&tmp[8];
  }
}

// x [B,V,C,HW] fp32 -> xb [B,V,HW,C] bf16  (q_in layout; kv_in via v-chunks)
__global__ __launch_bounds__(256) void prep_x(const float* __restrict__ x, short* __restrict__ xb){
  __shared__ short T[64*72];
  const int bv=blockIdx.z;
  tr_tile(x + (size_t)bv*C*HWS, HWS, xb + (size_t)bv*HWS*C, C,
          blockIdx.y*64, blockIdx.x*64, T, threadIdx.x);
}

// W [R][C] fp32 -> WT [C][R] bf16 for all four weights in one launch
__global__ __launch_bounds__(256) void prep_w(const float* Wq,const float* Wk,const float* Wv,const float* Wo,
                                              short* WqT, short* WkT, short* WvT, short* WoT){
  __shared__ short T[64*72];
  const int z=blockIdx.y;
  const float* in; short* out; int R;
  if(z==0){in=Wq; out=WqT; R=C;}
  else if(z==1){in=Wo; out=WoT; R=C;}
  else if(z==2){in=Wk; out=WkT; R=VC;}
  else         {in=Wv; out=WvT; R=VC;}
  const int tilesC=C/64, ntiles=(R/64)*tilesC;
  const int tile=blockIdx.x;
  if(tile>=ntiles) return;
  tr_tile(in, C, out, R, (tile/tilesC)*64, (tile%tilesC)*64, T, threadIdx.x);
}

// ---------------------------------------------------------------------------
// MFMA GEMM, tile 128x64, BK=64, 4 waves (each 32 rows x 64 cols).
// MODE 0: out bf16 = (acc+bias)*QSCALE  (Q-proj; attn 1/8 and 1/ln2 folded in)
// MODE 1: out fp32 = acc+bias+xres      (O-proj + residual)
// ---------------------------------------------------------------------------
template<int MODE>
__global__ __launch_bounds__(256) void qo_gemm(const short* __restrict__ A, const short* __restrict__ BT,
                                               const float* __restrict__ bias, const float* __restrict__ xres,
                                               void* __restrict__ outv){
  __shared__ __align__(16) short As[128*72];
  __shared__ __align__(16) short Bs[64*72];
  const int n0=blockIdx.x*64, r0=blockIdx.y*128;
  const int t=threadIdx.x, lane=t&63, w=t>>6, quad=lane>>4, ln=lane&15;

  f32x4 acc[2][4];
  #pragma unroll
  for(int rt=0;rt<2;rt++)
    #pragma unroll
    for(int nt=0;nt<4;nt++) acc[rt][nt]=(f32x4)0.f;

  for(int k0=0;k0<C;k0+=64){
    if(k0) __syncthreads();
    { const int r=t>>1, c=(t&1)*32;
      const short* p = A + (size_t)(r0+r)*C + k0 + c;
      #pragma unroll
      for(int j=0;j<4;j++) *(short8*)&As[r*72+c+j*8] = *(const short8*)(p+j*8);
    }
    { const int n=t>>2, c=(t&3)*16;
      const short* p = BT + (size_t)(n0+n)*C + k0 + c;
      *(short8*)&Bs[n*72+c]   = *(const short8*)p;
      *(short8*)&Bs[n*72+c+8] = *(const short8*)(p+8);
    }
    __syncthreads();
    #pragma unroll
    for(int s=0;s<2;s++){
      short8 af0=*(short8*)&As[(w*32+ln)*72    + s*32+quad*8];
      short8 af1=*(short8*)&As[(w*32+16+ln)*72 + s*32+quad*8];
      #pragma unroll
      for(int nt=0;nt<4;nt++){
        const short8 bf=*(short8*)&Bs[(nt*16+ln)*72 + s*32+quad*8];
        acc[0][nt]=__builtin_amdgcn_mfma_f32_16x16x32_bf16(af0,bf,acc[0][nt],0,0,0);
        acc[1][nt]=__builtin_amdgcn_mfma_f32_16x16x32_bf16(af1,bf,acc[1][nt],0,0,0);
      }
    }
  }

  constexpr float QSCALE = 0.18033688011112042f;  // 0.125 / ln(2): exp -> exp2
  float bcol[4];
  #pragma unroll
  for(int nt=0;nt<4;nt++) bcol[nt]=bias[n0+nt*16+ln];
  #pragma unroll
  for(int rt=0;rt<2;rt++)
    #pragma unroll
    for(int nt=0;nt<4;nt++)
      #pragma unroll
      for(int i=0;i<4;i++){
        const int row=r0+w*32+rt*16+quad*4+i, col=n0+nt*16+ln;
        const float vv=acc[rt][nt][i]+bcol[nt];
        if constexpr(MODE==0) ((short*)outv)[(size_t)row*C+col]=f2bf(vv*QSCALE);
        else ((float*)outv)[(size_t)row*C+col]=vv + xres[(size_t)row*C+col];
      }
}

// ---------------------------------------------------------------------------
// Fused K+V projection (as R3). K row-major bf16; V transposed vT[b][ch][hw].
// ---------------------------------------------------------------------------
__global__ __launch_bounds__(256) void kv_gemm(const short* __restrict__ xb,
                                               const short* __restrict__ WkT, const short* __restrict__ WvT,
                                               const float* __restrict__ bk, const float* __restrict__ bv,
                                               short* __restrict__ kO, short* __restrict__ vT){
  __shared__ __align__(16) short As[64*72], Bk[64*72], Bv[64*72], Ve[64*72];
  const int n0=blockIdx.x*64, r0=blockIdx.y*64;
  const int b=r0>>10, hw0=r0&1023;
  const int t=threadIdx.x, lane=t&63, w=t>>6, quad=lane>>4, ln=lane&15;

  f32x4 ak[4], av[4];
  #pragma unroll
  for(int nt=0;nt<4;nt++){ ak[nt]=(f32x4)0.f; av[nt]=(f32x4)0.f; }

  const int sr=t>>2, sc=(t&3)*16;
  for(int k0=0;k0<VC;k0+=64){
    if(k0) __syncthreads();
    const int v=k0>>8, c0=k0&255;
    { const short* p = xb + (size_t)((b*V+v)*HWS + hw0+sr)*C + c0 + sc;
      *(short8*)&As[sr*72+sc]   = *(const short8*)p;
      *(short8*)&As[sr*72+sc+8] = *(const short8*)(p+8); }
    { const short* p = WkT + (size_t)(n0+sr)*VC + k0 + sc;
      *(short8*)&Bk[sr*72+sc]   = *(const short8*)p;
      *(short8*)&Bk[sr*72+sc+8] = *(const short8*)(p+8); }
    { const short* p = WvT + (size_t)(n0+sr)*VC + k0 + sc;
      *(short8*)&Bv[sr*72+sc]   = *(const short8*)p;
      *(short8*)&Bv[sr*72+sc+8] = *(const short8*)(p+8); }
    __syncthreads();
    #pragma unroll
    for(int s=0;s<2;s++){
      const short8 af=*(short8*)&As[(w*16+ln)*72 + s*32+quad*8];
      #pragma unroll
      for(int nt=0;nt<4;nt++){
        const short8 kf=*(short8*)&Bk[(nt*16+ln)*72 + s*32+quad*8];
        const short8 vf=*(short8*)&Bv[(nt*16+ln)*72 + s*32+quad*8];
        ak[nt]=__builtin_amdgcn_mfma_f32_16x16x32_bf16(af,kf,ak[nt],0,0,0);
        av[nt]=__builtin_amdgcn_mfma_f32_16x16x32_bf16(af,vf,av[nt],0,0,0);
      }
    }
  }

  float bkc[4], bvc[4];
  #pragma unroll
  for(int nt=0;nt<4;nt++){ bkc[nt]=bk[n0+nt*16+ln]; bvc[nt]=bv[n0+nt*16+ln]; }

  #pragma unroll
  for(int nt=0;nt<4;nt++)
    #pragma unroll
    for(int i=0;i<4;i++){
      const int row=r0+w*16+quad*4+i, col=n0+nt*16+ln;
      kO[(size_t)row*C+col]=f2bf(ak[nt][i]+bkc[nt]);
    }

  __syncthreads();
  #pragma unroll
  for(int nt=0;nt<4;nt++)
    #pragma unroll
    for(int i=0;i<4;i++)
      Ve[(nt*16+ln)*72 + w*16+quad*4+i]=f2bf(av[nt][i]+bvc[nt]);
  __syncthreads();
  { const int ch=t>>2, hc=(t&3)*16;
    short* o = vT + (size_t)(b*C + n0+ch)*HWS + hw0 + hc;
    *(short8*)o     = *(short8*)&Ve[ch*72+hc];
    *(short8*)(o+8) = *(short8*)&Ve[ch*72+hc+8]; }
}

// ---------------------------------------------------------------------------
// LDS-free-main-loop MFMA attention.
// S^T = K·Q^T via 16x16x32 (A=K frags straight from global, B=Q regs);
// the S^T C-frag (row=key=quad*4+i, col=qrow=ln) IS the B-frag layout of
// mfma_f32_16x16x16bf16_1k, so P^T feeds O^T = V^T·P^T from registers.
// Each wave owns 16 keys of each 64-key tile, all 64 q-rows. No LDS, no
// barriers in the loop. Cross-wave O/l reduction once at the end (18 KB LDS).
// Q was pre-scaled by 0.125/ln2 -> softmax via raw v_exp_f32 (exp2).
// Mask (faithful): window keys SUPPRESSED.
// ---------------------------------------------------------------------------
__global__ __launch_bounds__(256) void attn_k(const short* __restrict__ q, const short* __restrict__ kk,
                                              const short* __restrict__ vT, short* __restrict__ ao){
  __shared__ float obuf[64*68];   // [dim][qrow], pitch 68
  __shared__ float lbuf[4][64];
  const int blk=blockIdx.x;
  // XCD swizzle: blk%8 ~ XCD; give each XCD 2 of the 16 (b,h) groups
  const int bh=(blk&7)*2 + ((blk>>3)&1);
  const int qt=blk>>4;
  const int b=bh>>2, h=bh&3;
  const int s0=qt*64;
  const int t=threadIdx.x, lane=t&63, w=t>>6, quad=lane>>4, ln=lane&15;

  // Q B-frags, loop-invariant (B[k=dim][n=qrow]: n=ln, k=quad*8+j)
  short8 qf[4][2];
  #pragma unroll
  for(int nt=0;nt<4;nt++)
    #pragma unroll
    for(int s=0;s<2;s++)
      qf[nt][s]=*(const short8*)&q[(size_t)(b*S+s0+nt*16+ln)*C + h*HD + s*32+quad*8];

  f32x4 o[4][4];   // [dt][nt] of O^T[dim][qrow]
  #pragma unroll
  for(int dt=0;dt<4;dt++)
    #pragma unroll
    for(int nt=0;nt<4;nt++) o[dt][nt]=(f32x4)0.f;
  float l[4]={0.f,0.f,0.f,0.f};

  // wave's key rows: j0 + w*16 + [0,16)
  const short* kp = kk + (size_t)(b*HWS + w*16 + ln)*C + h*HD + quad*8;
  const short* vp = vT + (size_t)(b*C + h*HD)*HWS + w*16 + quad*4;

  for(int j0=0;j0<HWS;j0+=64){
    // K A-frags from global (A[m=key]: m=ln, k=quad*8+j)
    short8 kf0=*(const short8*)(kp);
    short8 kf1=*(const short8*)(kp+32);
    kp += 64*C;

    f32x4 sa[4];
    #pragma unroll
    for(int nt=0;nt<4;nt++) sa[nt]=(f32x4)0.f;
    #pragma unroll
    for(int nt=0;nt<4;nt++){
      sa[nt]=__builtin_amdgcn_mfma_f32_16x16x32_bf16(kf0,qf[nt][0],sa[nt],0,0,0);
      sa[nt]=__builtin_amdgcn_mfma_f32_16x16x32_bf16(kf1,qf[nt][1],sa[nt],0,0,0);
    }

    // faithful window mask: suppress keys in [ig-3, ig+3]
    const int kmin=j0+w*16;
    if(kmin+15 >= s0-3 && kmin <= s0+66){
      #pragma unroll
      for(int nt=0;nt<4;nt++){
        const int ig=s0+nt*16+ln;
        #pragma unroll
        for(int i=0;i<4;i++){
          const int jg=kmin+quad*4+i;
          if((unsigned)(jg-ig+3)<=6u) sa[nt][i]=-100.f;
        }
      }
    }

    // exp2 + l accumulation + pack P^T to bf16 (B-frag for 16x16x16)
    short4v pt[4];
    #pragma unroll
    for(int nt=0;nt<4;nt++){
      #pragma unroll
      for(int i=0;i<4;i++){
        const float p=__builtin_amdgcn_exp2f(sa[nt][i]);
        l[nt]+=p;
        union{float f;unsigned u;} pu; pu.f=p;
        pt[nt][i]=(short)(pu.u>>16);
      }
    }

    // V^T A-frags from global (A[m=dim]: m=ln, k=quad*4+j keys)
    #pragma unroll
    for(int dt=0;dt<4;dt++){
      const short4v vf=*(const short4v*)(vp + (size_t)(dt*16+ln)*HWS + j0);
      #pragma unroll
      for(int nt=0;nt<4;nt++)
        o[dt][nt]=__builtin_amdgcn_mfma_f32_16x16x16bf16_1k(vf,pt[nt],o[dt][nt],0,0,0);
    }
  }

  // ---- cross-wave reduction ----
  // l: reduce across quads (same ln, 4 quads)
  #pragma unroll
  for(int nt=0;nt<4;nt++){
    l[nt]+=__shfl_xor(l[nt],16);
    l[nt]+=__shfl_xor(l[nt],32);
  }
  if(quad==0){
    #pragma unroll
    for(int nt=0;nt<4;nt++) lbuf[w][nt*16+ln]=l[nt];
  }
  // O: wave-sequential accumulate into obuf
  for(int r=0;r<4;r++){
    if(w==r){
      #pragma unroll
      for(int dt=0;dt<4;dt++)
        #pragma unroll
        for(int nt=0;nt<4;nt++)
          #pragma unroll
          for(int i=0;i<4;i++){
            const int idx=(dt*16+quad*4+i)*68 + nt*16+ln;
            if(r==0) obuf[idx]=o[dt][nt][i]; else obuf[idx]+=o[dt][nt][i];
          }
    }
    __syncthreads();
  }

  // normalize + store bf16 row-major
  {
    const int row=t>>2, dg=t&3;
    const float linv=1.0f/(lbuf[0][row]+lbuf[1][row]+lbuf[2][row]+lbuf[3][row]);
    short tmp[16];
    #pragma unroll
    for(int j=0;j<16;j++) tmp[j]=f2bf(obuf[(dg*16+j)*68+row]*linv);
    short* op = ao + (size_t)(b*S+s0+row)*C + h*HD + dg*16;
    *(short8*)op     = *(short8*)&tmp[0];
    *(short8*)(op+8) = *(short8*)&tmp[8];
  }
}

}  // namespace

extern "C" void kernel_launch(void* const* d_in, const int* in_sizes, int n_in,
                              void* d_out, int out_size, void* d_ws, size_t ws_size,
                              hipStream_t stream) {
  const float* x  = (const float*)d_in[0];
  const float* Wq = (const float*)d_in[1];
  const float* bq = (const float*)d_in[2];
  const float* Wk = (const float*)d_in[3];
  const float* bk = (const float*)d_in[4];
  const float* Wv = (const float*)d_in[5];
  const float* bv = (const float*)d_in[6];
  const float* Wo = (const float*)d_in[7];
  const float* bo = (const float*)d_in[8];
  float* out = (float*)d_out;

  char* p = (char*)d_ws;
  const size_t szBS=(size_t)B*S*C*2, szK=(size_t)B*HWS*C*2;
  short* xb =(short*)p; p+=szBS;
  short* qb =(short*)p; p+=szBS;
  short* aob=(short*)p; p+=szBS;
  short* kb =(short*)p; p+=szK;
  short* vTb=(short*)p; p+=szK;
  short* WqT=(short*)p; p+=(size_t)C*C*2;
  short* WoT=(short*)p; p+=(size_t)C*C*2;
  short* WkT=(short*)p; p+=(size_t)C*VC*2;
  short* WvT=(short*)p; p+=(size_t)C*VC*2;

  prep_x<<<dim3(16,4,B*V), 256, 0, stream>>>(x, xb);
  prep_w<<<dim3(96,4),     256, 0, stream>>>(Wq,Wk,Wv,Wo, WqT,WkT,WvT,WoT);
  qo_gemm<0><<<dim3(4, (B*S)/128), 256, 0, stream>>>(xb, WqT, bq, nullptr, qb);
  kv_gemm<<<dim3(4, (B*HWS)/64),  256, 0, stream>>>(xb, WkT, WvT, bk, bv, kb, vTb);
  attn_k<<<dim3(B*NH*(S/64)),     256, 0, stream>>>(qb, kb, vTb, aob);
  qo_gemm<1><<<dim3(4, (B*S)/128), 256, 0, stream>>>(aob, WoT, bo, x, out);
}

// Round 5
// 203.573 us; speedup vs baseline: 1.1716x; 1.1716x over previous
//
#include <hip/hip_runtime.h>
#include <cstddef>

namespace {

constexpr int B=4, V=6, C=256, HWS=1024, S=6144, NH=4, HD=64, VC=1536;

typedef short short8  __attribute__((ext_vector_type(8)));
typedef short short4v __attribute__((ext_vector_type(4)));
typedef float f32x4   __attribute__((ext_vector_type(4)));

__device__ inline short f2bf(float f){
  union{float f; unsigned u;} v; v.f=f;
  unsigned r = v.u + 0x7fffu + ((v.u>>16)&1u);   // RNE
  return (short)(r>>16);
}

// ---------------------------------------------------------------------------
// 64x64 transpose-cast tile: fp32 in[R][Cc] -> bf16 out[Cc][R].
// ---------------------------------------------------------------------------
__device__ inline void tr_tile(const float* in, int inRow, short* out, int outRow,
                               int r0, int c0, short* T /*64*72*/, int t){
  {
    const int rr=t>>2, cc=(t&3)*16;
    const float* p = in + (size_t)(r0+rr)*inRow + c0 + cc;
    short tmp[16];
    #pragma unroll
    for(int j=0;j<4;j++){
      const float4 f=*(const float4*)(p+j*4);
      tmp[j*4+0]=f2bf(f.x); tmp[j*4+1]=f2bf(f.y);
      tmp[j*4+2]=f2bf(f.z); tmp[j*4+3]=f2bf(f.w);
    }
    *(short8*)&T[rr*72+cc]   = *(short8*)&tmp[0];
    *(short8*)&T[rr*72+cc+8] = *(short8*)&tmp[8];
  }
  __syncthreads();
  {
    const int cc=t>>2, rr0=(t&3)*16;
    short tmp[16];
    #pragma unroll
    for(int j=0;j<16;j++) tmp[j]=T[(rr0+j)*72+cc];
    short* o = out + (size_t)(c0+cc)*outRow + r0 + rr0;
    *(short8*)o     = *(short8*)&tmp[0];
    *(short8*)(o+8) = *(short8*)&tmp[8];
  }
}

// x [B,V,C,HW] fp32 -> xb [B,V,HW,C] bf16  (q_in layout; kv_in via v-chunks)
__global__ __launch_bounds__(256) void prep_x(const float* __restrict__ x, short* __restrict__ xb){
  __shared__ short T[64*72];
  const int bv=blockIdx.z;
  tr_tile(x + (size_t)bv*C*HWS, HWS, xb + (size_t)bv*HWS*C, C,
          blockIdx.y*64, blockIdx.x*64, T, threadIdx.x);
}

// W [R][C] fp32 -> WT [C][R] bf16 for all four weights in one launch
__global__ __launch_bounds__(256) void prep_w(const float* Wq,const float* Wk,const float* Wv,const float* Wo,
                                              short* WqT, short* WkT, short* WvT, short* WoT){
  __shared__ short T[64*72];
  const int z=blockIdx.y;
  const float* in; short* out; int R;
  if(z==0){in=Wq; out=WqT; R=C;}
  else if(z==1){in=Wo; out=WoT; R=C;}
  else if(z==2){in=Wk; out=WkT; R=VC;}
  else         {in=Wv; out=WvT; R=VC;}
  const int tilesC=C/64, ntiles=(R/64)*tilesC;
  const int tile=blockIdx.x;
  if(tile>=ntiles) return;
  tr_tile(in, C, out, R, (tile/tilesC)*64, (tile%tilesC)*64, T, threadIdx.x);
}

// ---------------------------------------------------------------------------
// MFMA GEMM, tile 128x64, BK=64, 4 waves (each 32 rows x 64 cols).
// MODE 0: out bf16 = (acc+bias)*QSCALE  (Q-proj; attn 1/8 and 1/ln2 folded in)
// MODE 1: out fp32 = acc+bias+xres      (O-proj + residual)
// ---------------------------------------------------------------------------
template<int MODE>
__global__ __launch_bounds__(256) void qo_gemm(const short* __restrict__ A, const short* __restrict__ BT,
                                               const float* __restrict__ bias, const float* __restrict__ xres,
                                               void* __restrict__ outv){
  __shared__ __align__(16) short As[128*72];
  __shared__ __align__(16) short Bs[64*72];
  const int n0=blockIdx.x*64, r0=blockIdx.y*128;
  const int t=threadIdx.x, lane=t&63, w=t>>6, quad=lane>>4, ln=lane&15;

  f32x4 acc[2][4];
  #pragma unroll
  for(int rt=0;rt<2;rt++)
    #pragma unroll
    for(int nt=0;nt<4;nt++) acc[rt][nt]=(f32x4)0.f;

  for(int k0=0;k0<C;k0+=64){
    if(k0) __syncthreads();
    { const int r=t>>1, c=(t&1)*32;
      const short* p = A + (size_t)(r0+r)*C + k0 + c;
      #pragma unroll
      for(int j=0;j<4;j++) *(short8*)&As[r*72+c+j*8] = *(const short8*)(p+j*8);
    }
    { const int n=t>>2, c=(t&3)*16;
      const short* p = BT + (size_t)(n0+n)*C + k0 + c;
      *(short8*)&Bs[n*72+c]   = *(const short8*)p;
      *(short8*)&Bs[n*72+c+8] = *(const short8*)(p+8);
    }
    __syncthreads();
    #pragma unroll
    for(int s=0;s<2;s++){
      short8 af0=*(short8*)&As[(w*32+ln)*72    + s*32+quad*8];
      short8 af1=*(short8*)&As[(w*32+16+ln)*72 + s*32+quad*8];
      #pragma unroll
      for(int nt=0;nt<4;nt++){
        const short8 bf=*(short8*)&Bs[(nt*16+ln)*72 + s*32+quad*8];
        acc[0][nt]=__builtin_amdgcn_mfma_f32_16x16x32_bf16(af0,bf,acc[0][nt],0,0,0);
        acc[1][nt]=__builtin_amdgcn_mfma_f32_16x16x32_bf16(af1,bf,acc[1][nt],0,0,0);
      }
    }
  }

  constexpr float QSCALE = 0.18033688011112042f;  // 0.125 / ln(2): exp -> exp2
  float bcol[4];
  #pragma unroll
  for(int nt=0;nt<4;nt++) bcol[nt]=bias[n0+nt*16+ln];
  #pragma unroll
  for(int rt=0;rt<2;rt++)
    #pragma unroll
    for(int nt=0;nt<4;nt++)
      #pragma unroll
      for(int i=0;i<4;i++){
        const int row=r0+w*32+rt*16+quad*4+i, col=n0+nt*16+ln;
        const float vv=acc[rt][nt][i]+bcol[nt];
        if constexpr(MODE==0) ((short*)outv)[(size_t)row*C+col]=f2bf(vv*QSCALE);
        else ((float*)outv)[(size_t)row*C+col]=vv + xres[(size_t)row*C+col];
      }
}

// ---------------------------------------------------------------------------
// Fused K+V projection -> fragment-packed outputs for attn.
// Tile 64(hw=keys) x 64(ch = one head), BK=64, K=1536.
// Kpack[(bh*64+kt)*1024 + half*512 + lane*8] : 16x16x32 A-frag order
//   (lane=(quad,ln): key=ln, dims half*32+quad*8+[0,8))  [via LDS transpose]
// Vpack[(bh*64+kt)*1024 + dt*256 + lane*4]  : 16x16x16 A-frag order
//   (lane: dim=dt*16+ln... wait-free: av[nt] C-layout == frag layout, direct)
// ---------------------------------------------------------------------------
__global__ __launch_bounds__(256) void kv_gemm(const short* __restrict__ xb,
                                               const short* __restrict__ WkT, const short* __restrict__ WvT,
                                               const float* __restrict__ bk, const float* __restrict__ bv,
                                               short* __restrict__ Kpack, short* __restrict__ Vpack){
  __shared__ __align__(16) short As[64*72], Bk[64*72], Bv[64*72];
  const int n0=blockIdx.x*64, r0=blockIdx.y*64;
  const int b=r0>>10, hw0=r0&1023;
  const int h=n0>>6, bh=b*NH+h;
  const int t=threadIdx.x, lane=t&63, w=t>>6, quad=lane>>4, ln=lane&15;

  f32x4 ak[4], av[4];
  #pragma unroll
  for(int nt=0;nt<4;nt++){ ak[nt]=(f32x4)0.f; av[nt]=(f32x4)0.f; }

  const int sr=t>>2, sc=(t&3)*16;
  for(int k0=0;k0<VC;k0+=64){
    if(k0) __syncthreads();
    const int v=k0>>8, c0=k0&255;
    { const short* p = xb + (size_t)((b*V+v)*HWS + hw0+sr)*C + c0 + sc;
      *(short8*)&As[sr*72+sc]   = *(const short8*)p;
      *(short8*)&As[sr*72+sc+8] = *(const short8*)(p+8); }
    { const short* p = WkT + (size_t)(n0+sr)*VC + k0 + sc;
      *(short8*)&Bk[sr*72+sc]   = *(const short8*)p;
      *(short8*)&Bk[sr*72+sc+8] = *(const short8*)(p+8); }
    { const short* p = WvT + (size_t)(n0+sr)*VC + k0 + sc;
      *(short8*)&Bv[sr*72+sc]   = *(const short8*)p;
      *(short8*)&Bv[sr*72+sc+8] = *(const short8*)(p+8); }
    __syncthreads();
    #pragma unroll
    for(int s=0;s<2;s++){
      const short8 af=*(short8*)&As[(w*16+ln)*72 + s*32+quad*8];
      #pragma unroll
      for(int nt=0;nt<4;nt++){
        const short8 kf=*(short8*)&Bk[(nt*16+ln)*72 + s*32+quad*8];
        const short8 vf=*(short8*)&Bv[(nt*16+ln)*72 + s*32+quad*8];
        ak[nt]=__builtin_amdgcn_mfma_f32_16x16x32_bf16(af,kf,ak[nt],0,0,0);
        av[nt]=__builtin_amdgcn_mfma_f32_16x16x32_bf16(af,vf,av[nt],0,0,0);
      }
    }
  }

  float bkc[4], bvc[4];
  #pragma unroll
  for(int nt=0;nt<4;nt++){ bkc[nt]=bk[n0+nt*16+ln]; bvc[nt]=bv[n0+nt*16+ln]; }

  // ---- V: C-layout (key=quad*4+i, dim=nt*16+ln) IS the PV A-frag mapping.
  // Wave w owns keys w*16..+15 -> kt=(hw0>>4)+w. Coalesced b64 stores.
  {
    short* vq = Vpack + ((size_t)(bh*64 + (hw0>>4) + w))*1024;
    #pragma unroll
    for(int nt=0;nt<4;nt++){
      short4v vp;
      #pragma unroll
      for(int i=0;i<4;i++) vp[i]=f2bf(av[nt][i]+bvc[nt]);
      *(short4v*)(vq + nt*256 + lane*4) = vp;
    }
  }

  // ---- K: transpose C-layout -> A-frag order via LDS (reuse As)
  __syncthreads();
  #pragma unroll
  for(int nt=0;nt<4;nt++)
    #pragma unroll
    for(int i=0;i<4;i++)
      As[(w*16+quad*4+i)*72 + nt*16+ln] = f2bf(ak[nt][i]+bkc[nt]);
  __syncthreads();
  {
    short* kp = Kpack + ((size_t)(bh*64 + (hw0>>4) + w))*1024;
    #pragma unroll
    for(int half=0; half<2; half++){
      const short8 f = *(short8*)&As[(w*16+ln)*72 + half*32 + quad*8];
      *(short8*)(kp + half*512 + lane*8) = f;
    }
  }
}

// ---------------------------------------------------------------------------
// Zero-LDS-main-loop MFMA attention with fragment-packed K/V.
// S^T = K·Q^T (16x16x32); S^T C-frag == B-frag of 16x16x16bf16_1k, so
// P^T feeds O^T = V^T·P^T from registers. Per tile: 2 coalesced b128 (K),
// 4 coalesced b64 (V), all L2-hot; register double-buffered; no barriers.
// Q pre-scaled by 0.125/ln2 -> softmax via exp2. Faithful window suppression.
// ---------------------------------------------------------------------------
__global__ __launch_bounds__(256) void attn_k(const short* __restrict__ q, const short* __restrict__ Kpack,
                                              const short* __restrict__ Vpack, short* __restrict__ ao){
  __shared__ float obuf[64*68];   // [dim][qrow], pitch 68
  __shared__ float lbuf[4][64];
  const int blk=blockIdx.x;
  const int bh=(blk&7)*2 + ((blk>>3)&1);   // XCD-locality swizzle
  const int qt=blk>>4;
  const int b=bh>>2, h=bh&3;
  const int s0=qt*64;
  const int t=threadIdx.x, lane=t&63, w=t>>6, quad=lane>>4, ln=lane&15;

  // Q B-frags, loop-invariant (B[k=dim][n=qrow]: n=ln, k=quad*8+j)
  short8 qf[4][2];
  #pragma unroll
  for(int nt=0;nt<4;nt++)
    #pragma unroll
    for(int s=0;s<2;s++)
      qf[nt][s]=*(const short8*)&q[(size_t)(b*S+s0+nt*16+ln)*C + h*HD + s*32+quad*8];

  f32x4 o[4][4];   // [dt][nt] of O^T[dim][qrow]
  #pragma unroll
  for(int dt=0;dt<4;dt++)
    #pragma unroll
    for(int nt=0;nt<4;nt++) o[dt][nt]=(f32x4)0.f;
  float l[4]={0.f,0.f,0.f,0.f};

  const short* kp = Kpack + ((size_t)(bh*64 + w))*1024;
  const short* vp = Vpack + ((size_t)(bh*64 + w))*1024;

  // pipeline: preload tile 0
  short8  kf0=*(const short8*)(kp + lane*8);
  short8  kf1=*(const short8*)(kp + 512 + lane*8);
  short4v vf[4];
  #pragma unroll
  for(int dt=0;dt<4;dt++) vf[dt]=*(const short4v*)(vp + dt*256 + lane*4);

  #pragma unroll 1
  for(int j0=0;j0<HWS;j0+=64){
    // prefetch next tile (advance 4 kt = 4096 shorts); last iter reloads same
    const size_t adv = (j0+64<HWS) ? 4096 : 0;
    kp += adv; vp += adv;
    const short8  nkf0=*(const short8*)(kp + lane*8);
    const short8  nkf1=*(const short8*)(kp + 512 + lane*8);
    short4v nvf[4];
    #pragma unroll
    for(int dt=0;dt<4;dt++) nvf[dt]=*(const short4v*)(vp + dt*256 + lane*4);

    f32x4 sa[4];
    #pragma unroll
    for(int nt=0;nt<4;nt++) sa[nt]=(f32x4)0.f;
    #pragma unroll
    for(int nt=0;nt<4;nt++){
      sa[nt]=__builtin_amdgcn_mfma_f32_16x16x32_bf16(kf0,qf[nt][0],sa[nt],0,0,0);
      sa[nt]=__builtin_amdgcn_mfma_f32_16x16x32_bf16(kf1,qf[nt][1],sa[nt],0,0,0);
    }

    // faithful window mask: suppress keys in [ig-3, ig+3]
    const int kmin=j0+w*16;
    if(kmin+15 >= s0-3 && kmin <= s0+66){
      #pragma unroll
      for(int nt=0;nt<4;nt++){
        const int ig=s0+nt*16+ln;
        #pragma unroll
        for(int i=0;i<4;i++){
          const int jg=kmin+quad*4+i;
          if((unsigned)(jg-ig+3)<=6u) sa[nt][i]=-100.f;
        }
      }
    }

    // exp2 + l accumulation + pack P^T (B-frag of 16x16x16)
    short4v pt[4];
    #pragma unroll
    for(int nt=0;nt<4;nt++){
      #pragma unroll
      for(int i=0;i<4;i++){
        const float p=__builtin_amdgcn_exp2f(sa[nt][i]);
        l[nt]+=p;
        union{float f;unsigned u;} pu; pu.f=p;
        pt[nt][i]=(short)(pu.u>>16);
      }
    }

    #pragma unroll
    for(int dt=0;dt<4;dt++)
      #pragma unroll
      for(int nt=0;nt<4;nt++)
        o[dt][nt]=__builtin_amdgcn_mfma_f32_16x16x16bf16_1k(vf[dt],pt[nt],o[dt][nt],0,0,0);

    kf0=nkf0; kf1=nkf1;
    #pragma unroll
    for(int dt=0;dt<4;dt++) vf[dt]=nvf[dt];
  }

  // ---- cross-wave reduction ----
  #pragma unroll
  for(int nt=0;nt<4;nt++){
    l[nt]+=__shfl_xor(l[nt],16);
    l[nt]+=__shfl_xor(l[nt],32);
  }
  if(quad==0){
    #pragma unroll
    for(int nt=0;nt<4;nt++) lbuf[w][nt*16+ln]=l[nt];
  }
  for(int r=0;r<4;r++){
    if(w==r){
      #pragma unroll
      for(int dt=0;dt<4;dt++)
        #pragma unroll
        for(int nt=0;nt<4;nt++)
          #pragma unroll
          for(int i=0;i<4;i++){
            const int idx=(dt*16+quad*4+i)*68 + nt*16+ln;
            if(r==0) obuf[idx]=o[dt][nt][i]; else obuf[idx]+=o[dt][nt][i];
          }
    }
    __syncthreads();
  }

  {
    const int row=t>>2, dg=t&3;
    const float linv=1.0f/(lbuf[0][row]+lbuf[1][row]+lbuf[2][row]+lbuf[3][row]);
    short tmp[16];
    #pragma unroll
    for(int j=0;j<16;j++) tmp[j]=f2bf(obuf[(dg*16+j)*68+row]*linv);
    short* op = ao + (size_t)(b*S+s0+row)*C + h*HD + dg*16;
    *(short8*)op     = *(short8*)&tmp[0];
    *(short8*)(op+8) = *(short8*)&tmp[8];
  }
}

}  // namespace

extern "C" void kernel_launch(void* const* d_in, const int* in_sizes, int n_in,
                              void* d_out, int out_size, void* d_ws, size_t ws_size,
                              hipStream_t stream) {
  const float* x  = (const float*)d_in[0];
  const float* Wq = (const float*)d_in[1];
  const float* bq = (const float*)d_in[2];
  const float* Wk = (const float*)d_in[3];
  const float* bk = (const float*)d_in[4];
  const float* Wv = (const float*)d_in[5];
  const float* bv = (const float*)d_in[6];
  const float* Wo = (const float*)d_in[7];
  const float* bo = (const float*)d_in[8];
  float* out = (float*)d_out;

  char* p = (char*)d_ws;
  const size_t szBS=(size_t)B*S*C*2, szK=(size_t)B*HWS*C*2;
  short* xb   =(short*)p; p+=szBS;
  short* qb   =(short*)p; p+=szBS;
  short* aob  =(short*)p; p+=szBS;
  short* Kpack=(short*)p; p+=szK;
  short* Vpack=(short*)p; p+=szK;
  short* WqT=(short*)p; p+=(size_t)C*C*2;
  short* WoT=(short*)p; p+=(size_t)C*C*2;
  short* WkT=(short*)p; p+=(size_t)C*VC*2;
  short* WvT=(short*)p; p+=(size_t)C*VC*2;

  prep_x<<<dim3(16,4,B*V), 256, 0, stream>>>(x, xb);
  prep_w<<<dim3(96,4),     256, 0, stream>>>(Wq,Wk,Wv,Wo, WqT,WkT,WvT,WoT);
  qo_gemm<0><<<dim3(4, (B*S)/128), 256, 0, stream>>>(xb, WqT, bq, nullptr, qb);
  kv_gemm<<<dim3(4, (B*HWS)/64),  256, 0, stream>>>(xb, WkT, WvT, bk, bv, Kpack, Vpack);
  attn_k<<<dim3(B*NH*(S/64)),     256, 0, stream>>>(qb, Kpack, Vpack, aob);
  qo_gemm<1><<<dim3(4, (B*S)/128), 256, 0, stream>>>(aob, WoT, bo, x, out);
}

// Round 6
// 196.266 us; speedup vs baseline: 1.2152x; 1.0372x over previous
//
#include <hip/hip_runtime.h>
#include <cstddef>

namespace {

constexpr int B=4, V=6, C=256, HWS=1024, S=6144, NH=4, HD=64, VC=1536;

typedef short short8  __attribute__((ext_vector_type(8)));
typedef short short4v __attribute__((ext_vector_type(4)));
typedef float f32x4   __attribute__((ext_vector_type(4)));

__device__ inline short f2bf(float f){
  union{float f; unsigned u;} v; v.f=f;
  unsigned r = v.u + 0x7fffu + ((v.u>>16)&1u);   // RNE
  return (short)(r>>16);
}
__device__ inline unsigned fbits(float f){
  union{float f; unsigned u;} v; v.f=f; return v.u;
}

// ---------------------------------------------------------------------------
// 64x64 transpose-cast tile: fp32 in[R][Cc] -> bf16 out[Cc][R].
// ---------------------------------------------------------------------------
__device__ inline void tr_tile(const float* in, int inRow, short* out, int outRow,
                               int r0, int c0, short* T /*64*72*/, int t){
  {
    const int rr=t>>2, cc=(t&3)*16;
    const float* p = in + (size_t)(r0+rr)*inRow + c0 + cc;
    short tmp[16];
    #pragma unroll
    for(int j=0;j<4;j++){
      const float4 f=*(const float4*)(p+j*4);
      tmp[j*4+0]=f2bf(f.x); tmp[j*4+1]=f2bf(f.y);
      tmp[j*4+2]=f2bf(f.z); tmp[j*4+3]=f2bf(f.w);
    }
    *(short8*)&T[rr*72+cc]   = *(short8*)&tmp[0];
    *(short8*)&T[rr*72+cc+8] = *(short8*)&tmp[8];
  }
  __syncthreads();
  {
    const int cc=t>>2, rr0=(t&3)*16;
    short tmp[16];
    #pragma unroll
    for(int j=0;j<16;j++) tmp[j]=T[(rr0+j)*72+cc];
    short* o = out + (size_t)(c0+cc)*outRow + r0 + rr0;
    *(short8*)o     = *(short8*)&tmp[0];
    *(short8*)(o+8) = *(short8*)&tmp[8];
  }
}

// Combined prep: blocks 0..1535 transpose-cast x; 1536+ transpose-cast weights.
__global__ __launch_bounds__(256) void prep(const float* __restrict__ x,
                                            const float* __restrict__ Wq, const float* __restrict__ Wk,
                                            const float* __restrict__ Wv, const float* __restrict__ Wo,
                                            short* __restrict__ xb, short* __restrict__ WqT,
                                            short* __restrict__ WkT, short* __restrict__ WvT,
                                            short* __restrict__ WoT){
  __shared__ short T[64*72];
  const int blk=blockIdx.x;
  if(blk<1536){
    const int bx=blk&15, by=(blk>>4)&3, bv=blk>>6;
    tr_tile(x + (size_t)bv*C*HWS, HWS, xb + (size_t)bv*HWS*C, C, by*64, bx*64, T, threadIdx.x);
  } else {
    const int idx=blk-1536;
    const int tile=idx%96, z=idx/96;
    const float* in; short* out; int R;
    if(z==0){in=Wq; out=WqT; R=C;}
    else if(z==1){in=Wo; out=WoT; R=C;}
    else if(z==2){in=Wk; out=WkT; R=VC;}
    else         {in=Wv; out=WvT; R=VC;}
    const int tilesC=C/64, ntiles=(R/64)*tilesC;
    if(tile>=ntiles) return;
    tr_tile(in, C, out, R, (tile/tilesC)*64, (tile%tilesC)*64, T, threadIdx.x);
  }
}

// ---------------------------------------------------------------------------
// qo GEMM body, tile 128x64, BK=64. MODE 0: bf16 out scaled; MODE 1: fp32+res.
// ---------------------------------------------------------------------------
template<int MODE>
__device__ inline void qo_body(const short* __restrict__ A, const short* __restrict__ BT,
                               const float* __restrict__ bias, const float* __restrict__ xres,
                               void* __restrict__ outv, short* As, short* Bs, int n0, int r0){
  const int t=threadIdx.x, lane=t&63, w=t>>6, quad=lane>>4, ln=lane&15;
  f32x4 acc[2][4];
  #pragma unroll
  for(int rt=0;rt<2;rt++)
    #pragma unroll
    for(int nt=0;nt<4;nt++) acc[rt][nt]=(f32x4)0.f;

  for(int k0=0;k0<C;k0+=64){
    if(k0) __syncthreads();
    { const int r=t>>1, c=(t&1)*32;
      const short* p = A + (size_t)(r0+r)*C + k0 + c;
      #pragma unroll
      for(int j=0;j<4;j++) *(short8*)&As[r*72+c+j*8] = *(const short8*)(p+j*8);
    }
    { const int n=t>>2, c=(t&3)*16;
      const short* p = BT + (size_t)(n0+n)*C + k0 + c;
      *(short8*)&Bs[n*72+c]   = *(const short8*)p;
      *(short8*)&Bs[n*72+c+8] = *(const short8*)(p+8);
    }
    __syncthreads();
    #pragma unroll
    for(int s=0;s<2;s++){
      short8 af0=*(short8*)&As[(w*32+ln)*72    + s*32+quad*8];
      short8 af1=*(short8*)&As[(w*32+16+ln)*72 + s*32+quad*8];
      #pragma unroll
      for(int nt=0;nt<4;nt++){
        const short8 bf=*(short8*)&Bs[(nt*16+ln)*72 + s*32+quad*8];
        acc[0][nt]=__builtin_amdgcn_mfma_f32_16x16x32_bf16(af0,bf,acc[0][nt],0,0,0);
        acc[1][nt]=__builtin_amdgcn_mfma_f32_16x16x32_bf16(af1,bf,acc[1][nt],0,0,0);
      }
    }
  }

  constexpr float QSCALE = 0.18033688011112042f;  // 0.125/ln2: softmax via exp2
  float bcol[4];
  #pragma unroll
  for(int nt=0;nt<4;nt++) bcol[nt]=bias[n0+nt*16+ln];
  #pragma unroll
  for(int rt=0;rt<2;rt++)
    #pragma unroll
    for(int nt=0;nt<4;nt++)
      #pragma unroll
      for(int i=0;i<4;i++){
        const int row=r0+w*32+rt*16+quad*4+i, col=n0+nt*16+ln;
        const float vv=acc[rt][nt][i]+bcol[nt];
        if constexpr(MODE==0) ((short*)outv)[(size_t)row*C+col]=f2bf(vv*QSCALE);
        else ((float*)outv)[(size_t)row*C+col]=vv + xres[(size_t)row*C+col];
      }
}

// ---------------------------------------------------------------------------
// Combined projection kernel.
// Blocks 0..255: fused K+V projection -> fragment-packed Kpack/Vpack.
// Blocks 256..1023: Q projection (128x64 tiles).
// kv blocks first: they're the long pole (24 K-iters vs 4).
// ---------------------------------------------------------------------------
__global__ __launch_bounds__(256) void proj(const short* __restrict__ xb,
                                            const short* __restrict__ WqT, const short* __restrict__ WkT,
                                            const short* __restrict__ WvT,
                                            const float* __restrict__ bq, const float* __restrict__ bk,
                                            const float* __restrict__ bv,
                                            short* __restrict__ qb, short* __restrict__ Kpack,
                                            short* __restrict__ Vpack){
  __shared__ __align__(16) short sh[13824];
  const int blk=blockIdx.x;
  const int t=threadIdx.x, lane=t&63, w=t>>6, quad=lane>>4, ln=lane&15;

  if(blk>=256){
    const int qblk=blk-256;
    qo_body<0>(xb, WqT, bq, nullptr, qb, sh, sh+9216, (qblk&3)*64, (qblk>>2)*128);
    return;
  }

  // ---- kv path ----
  short* As=sh; short* Bk=sh+4608; short* Bv=sh+9216;
  const int n0=(blk&3)*64, r0=(blk>>2)*64;
  const int b=r0>>10, hw0=r0&1023;
  const int h=n0>>6, bh=b*NH+h;

  f32x4 ak[4], av[4];
  #pragma unroll
  for(int nt=0;nt<4;nt++){ ak[nt]=(f32x4)0.f; av[nt]=(f32x4)0.f; }

  const int sr=t>>2, sc=(t&3)*16;
  for(int k0=0;k0<VC;k0+=64){
    if(k0) __syncthreads();
    const int v=k0>>8, c0=k0&255;
    { const short* p = xb + (size_t)((b*V+v)*HWS + hw0+sr)*C + c0 + sc;
      *(short8*)&As[sr*72+sc]   = *(const short8*)p;
      *(short8*)&As[sr*72+sc+8] = *(const short8*)(p+8); }
    { const short* p = WkT + (size_t)(n0+sr)*VC + k0 + sc;
      *(short8*)&Bk[sr*72+sc]   = *(const short8*)p;
      *(short8*)&Bk[sr*72+sc+8] = *(const short8*)(p+8); }
    { const short* p = WvT + (size_t)(n0+sr)*VC + k0 + sc;
      *(short8*)&Bv[sr*72+sc]   = *(const short8*)p;
      *(short8*)&Bv[sr*72+sc+8] = *(const short8*)(p+8); }
    __syncthreads();
    #pragma unroll
    for(int s=0;s<2;s++){
      const short8 af=*(short8*)&As[(w*16+ln)*72 + s*32+quad*8];
      #pragma unroll
      for(int nt=0;nt<4;nt++){
        const short8 kf=*(short8*)&Bk[(nt*16+ln)*72 + s*32+quad*8];
        const short8 vf=*(short8*)&Bv[(nt*16+ln)*72 + s*32+quad*8];
        ak[nt]=__builtin_amdgcn_mfma_f32_16x16x32_bf16(af,kf,ak[nt],0,0,0);
        av[nt]=__builtin_amdgcn_mfma_f32_16x16x32_bf16(af,vf,av[nt],0,0,0);
      }
    }
  }

  float bkc[4], bvc[4];
  #pragma unroll
  for(int nt=0;nt<4;nt++){ bkc[nt]=bk[n0+nt*16+ln]; bvc[nt]=bv[n0+nt*16+ln]; }

  // V: C-layout (key=quad*4+i, dim=nt*16+ln) IS the PV A-frag mapping.
  {
    short* vq = Vpack + ((size_t)(bh*64 + (hw0>>4) + w))*1024;
    #pragma unroll
    for(int nt=0;nt<4;nt++){
      short4v vp;
      #pragma unroll
      for(int i=0;i<4;i++) vp[i]=f2bf(av[nt][i]+bvc[nt]);
      *(short4v*)(vq + nt*256 + lane*4) = vp;
    }
  }

  // K: transpose C-layout -> A-frag order via LDS (reuse As)
  __syncthreads();
  #pragma unroll
  for(int nt=0;nt<4;nt++)
    #pragma unroll
    for(int i=0;i<4;i++)
      As[(w*16+quad*4+i)*72 + nt*16+ln] = f2bf(ak[nt][i]+bkc[nt]);
  __syncthreads();
  {
    short* kp = Kpack + ((size_t)(bh*64 + (hw0>>4) + w))*1024;
    #pragma unroll
    for(int half=0; half<2; half++){
      const short8 f = *(short8*)&As[(w*16+ln)*72 + half*32 + quad*8];
      *(short8*)(kp + half*512 + lane*8) = f;
    }
  }
}

// ---------------------------------------------------------------------------
// Zero-LDS-main-loop MFMA attention, fragment-packed K/V.
// Trims vs R5: perm-based bf16 pack (1 v_perm / pair), z4 C-operand init,
// f32x4 l accumulation, 2x-unrolled ping-pong K frags (no reg copies),
// V frags loaded at tile top (latency hidden under QK+exp of same tile).
// ---------------------------------------------------------------------------
__global__ __launch_bounds__(256) void attn_k(const short* __restrict__ q, const short* __restrict__ Kpack,
                                              const short* __restrict__ Vpack, short* __restrict__ ao){
  __shared__ float obuf[64*68];   // [dim][qrow]
  __shared__ float lbuf[4][64];
  const int blk=blockIdx.x;
  const int bh=(blk&7)*2 + ((blk>>3)&1);   // XCD-locality swizzle
  const int qt=blk>>4;
  const int b=bh>>2, h=bh&3;
  const int s0=qt*64;
  const int t=threadIdx.x, lane=t&63, w=t>>6, quad=lane>>4, ln=lane&15;

  short8 qf[4][2];
  #pragma unroll
  for(int nt=0;nt<4;nt++)
    #pragma unroll
    for(int s=0;s<2;s++)
      qf[nt][s]=*(const short8*)&q[(size_t)(b*S+s0+nt*16+ln)*C + h*HD + s*32+quad*8];

  f32x4 o[4][4];
  #pragma unroll
  for(int dt=0;dt<4;dt++)
    #pragma unroll
    for(int nt=0;nt<4;nt++) o[dt][nt]=(f32x4)0.f;
  f32x4 l4[4];
  #pragma unroll
  for(int nt=0;nt<4;nt++) l4[nt]=(f32x4)0.f;

  const short* kbase = Kpack + ((size_t)(bh*64+w))*1024;
  const short* vbase = Vpack + ((size_t)(bh*64+w))*1024;
  const f32x4 z4=(f32x4)0.f;

  short8 kfa0=*(const short8*)(kbase + lane*8);
  short8 kfa1=*(const short8*)(kbase + 512 + lane*8);
  short8 kfb0=*(const short8*)(kbase + 4096 + lane*8);
  short8 kfb1=*(const short8*)(kbase + 4096 + 512 + lane*8);

#define ATTN_TILE(KF0,KF1,TI,PI)                                              \
  {                                                                           \
    const short* vp = vbase + (size_t)(TI)*4096;                              \
    short4v vf[4];                                                            \
    _Pragma("unroll")                                                         \
    for(int dt=0;dt<4;dt++) vf[dt]=*(const short4v*)(vp + dt*256 + lane*4);   \
    f32x4 sa[4];                                                              \
    _Pragma("unroll")                                                         \
    for(int nt=0;nt<4;nt++){                                                  \
      sa[nt]=__builtin_amdgcn_mfma_f32_16x16x32_bf16(KF0,qf[nt][0],z4,0,0,0); \
      sa[nt]=__builtin_amdgcn_mfma_f32_16x16x32_bf16(KF1,qf[nt][1],sa[nt],0,0,0); \
    }                                                                         \
    const size_t poff=(size_t)(PI)*4096;                                      \
    KF0=*(const short8*)(kbase + poff + lane*8);                              \
    KF1=*(const short8*)(kbase + poff + 512 + lane*8);                        \
    const int kmin=(TI)*64 + w*16;                                            \
    if(kmin+15 >= s0-3 && kmin <= s0+66){                                     \
      _Pragma("unroll")                                                       \
      for(int nt=0;nt<4;nt++){                                                \
        const int ig=s0+nt*16+ln;                                             \
        _Pragma("unroll")                                                     \
        for(int i=0;i<4;i++){                                                 \
          const int jg=kmin+quad*4+i;                                         \
          if((unsigned)(jg-ig+3)<=6u) sa[nt][i]=-100.f;                       \
        }                                                                     \
      }                                                                       \
    }                                                                         \
    short4v pt[4];                                                            \
    _Pragma("unroll")                                                         \
    for(int nt=0;nt<4;nt++){                                                  \
      f32x4 pv;                                                               \
      _Pragma("unroll")                                                       \
      for(int i=0;i<4;i++) pv[i]=__builtin_amdgcn_exp2f(sa[nt][i]);           \
      l4[nt]+=pv;                                                             \
      union{ short4v s; unsigned u[2]; } P;                                   \
      P.u[0]=__builtin_amdgcn_perm(fbits(pv[1]), fbits(pv[0]), 0x07060302u);  \
      P.u[1]=__builtin_amdgcn_perm(fbits(pv[3]), fbits(pv[2]), 0x07060302u);  \
      pt[nt]=P.s;                                                             \
    }                                                                         \
    _Pragma("unroll")                                                         \
    for(int dt=0;dt<4;dt++)                                                   \
      _Pragma("unroll")                                                       \
      for(int nt=0;nt<4;nt++)                                                 \
        o[dt][nt]=__builtin_amdgcn_mfma_f32_16x16x16bf16_1k(vf[dt],pt[nt],o[dt][nt],0,0,0); \
  }

  #pragma unroll 1
  for(int i=0;i<16;i+=2){
    const int ipa = (i+2<16)? i+2 : i;
    const int ipb = (i+3<16)? i+3 : i+1;
    ATTN_TILE(kfa0,kfa1,i,ipa)
    ATTN_TILE(kfb0,kfb1,i+1,ipb)
  }
#undef ATTN_TILE

  // ---- cross-wave reduction ----
  float l[4];
  #pragma unroll
  for(int nt=0;nt<4;nt++){
    l[nt]=l4[nt][0]+l4[nt][1]+l4[nt][2]+l4[nt][3];
    l[nt]+=__shfl_xor(l[nt],16);
    l[nt]+=__shfl_xor(l[nt],32);
  }
  if(quad==0){
    #pragma unroll
    for(int nt=0;nt<4;nt++) lbuf[w][nt*16+ln]=l[nt];
  }
  for(int r=0;r<4;r++){
    if(w==r){
      #pragma unroll
      for(int dt=0;dt<4;dt++)
        #pragma unroll
        for(int nt=0;nt<4;nt++)
          #pragma unroll
          for(int i=0;i<4;i++){
            const int idx=(dt*16+quad*4+i)*68 + nt*16+ln;
            if(r==0) obuf[idx]=o[dt][nt][i]; else obuf[idx]+=o[dt][nt][i];
          }
    }
    __syncthreads();
  }

  {
    const int row=t>>2, dg=t&3;
    const float linv=1.0f/(lbuf[0][row]+lbuf[1][row]+lbuf[2][row]+lbuf[3][row]);
    short tmp[16];
    #pragma unroll
    for(int j=0;j<16;j++) tmp[j]=f2bf(obuf[(dg*16+j)*68+row]*linv);
    short* op = ao + (size_t)(b*S+s0+row)*C + h*HD + dg*16;
    *(short8*)op     = *(short8*)&tmp[0];
    *(short8*)(op+8) = *(short8*)&tmp[8];
  }
}

// O-projection + residual (MODE 1 wrapper)
__global__ __launch_bounds__(256) void o_gemm(const short* __restrict__ A, const short* __restrict__ BT,
                                              const float* __restrict__ bias, const float* __restrict__ xres,
                                              float* __restrict__ out){
  __shared__ __align__(16) short sh[13824];
  qo_body<1>(A, BT, bias, xres, out, sh, sh+9216, (int)(blockIdx.x&3)*64, (int)(blockIdx.x>>2)*128);
}

}  // namespace

extern "C" void kernel_launch(void* const* d_in, const int* in_sizes, int n_in,
                              void* d_out, int out_size, void* d_ws, size_t ws_size,
                              hipStream_t stream) {
  const float* x  = (const float*)d_in[0];
  const float* Wq = (const float*)d_in[1];
  const float* bq = (const float*)d_in[2];
  const float* Wk = (const float*)d_in[3];
  const float* bk = (const float*)d_in[4];
  const float* Wv = (const float*)d_in[5];
  const float* bv = (const float*)d_in[6];
  const float* Wo = (const float*)d_in[7];
  const float* bo = (const float*)d_in[8];
  float* out = (float*)d_out;

  char* p = (char*)d_ws;
  const size_t szBS=(size_t)B*S*C*2, szK=(size_t)B*HWS*C*2;
  short* xb   =(short*)p; p+=szBS;
  short* qb   =(short*)p; p+=szBS;
  short* aob  =(short*)p; p+=szBS;
  short* Kpack=(short*)p; p+=szK;
  short* Vpack=(short*)p; p+=szK;
  short* WqT=(short*)p; p+=(size_t)C*C*2;
  short* WoT=(short*)p; p+=(size_t)C*C*2;
  short* WkT=(short*)p; p+=(size_t)C*VC*2;
  short* WvT=(short*)p; p+=(size_t)C*VC*2;

  prep<<<dim3(1920), 256, 0, stream>>>(x, Wq,Wk,Wv,Wo, xb, WqT,WkT,WvT,WoT);
  proj<<<dim3(1024), 256, 0, stream>>>(xb, WqT,WkT,WvT, bq,bk,bv, qb, Kpack, Vpack);
  attn_k<<<dim3(B*NH*(S/64)), 256, 0, stream>>>(qb, Kpack, Vpack, aob);
  o_gemm<<<dim3(4*((B*S)/128)), 256, 0, stream>>>(aob, WoT, bo, x, out);
}

// Round 7
// 190.224 us; speedup vs baseline: 1.2538x; 1.0318x over previous
//
#include <hip/hip_runtime.h>
#include <cstddef>

namespace {

constexpr int B=4, V=6, C=256, HWS=1024, S=6144, NH=4, HD=64, VC=1536;

typedef short short8  __attribute__((ext_vector_type(8)));
typedef short short4v __attribute__((ext_vector_type(4)));
typedef float f32x4   __attribute__((ext_vector_type(4)));

__device__ inline short f2bf(float f){
  union{float f; unsigned u;} v; v.f=f;
  unsigned r = v.u + 0x7fffu + ((v.u>>16)&1u);   // RNE
  return (short)(r>>16);
}
__device__ inline unsigned fbits(float f){
  union{float f; unsigned u;} v; v.f=f; return v.u;
}

// ---------------------------------------------------------------------------
// 64x64 transpose-cast tile: fp32 in[R][Cc] -> bf16 out[Cc][R].
// ---------------------------------------------------------------------------
__device__ inline void tr_tile(const float* in, int inRow, short* out, int outRow,
                               int r0, int c0, short* T /*64*72*/, int t){
  {
    const int rr=t>>2, cc=(t&3)*16;
    const float* p = in + (size_t)(r0+rr)*inRow + c0 + cc;
    short tmp[16];
    #pragma unroll
    for(int j=0;j<4;j++){
      const float4 f=*(const float4*)(p+j*4);
      tmp[j*4+0]=f2bf(f.x); tmp[j*4+1]=f2bf(f.y);
      tmp[j*4+2]=f2bf(f.z); tmp[j*4+3]=f2bf(f.w);
    }
    *(short8*)&T[rr*72+cc]   = *(short8*)&tmp[0];
    *(short8*)&T[rr*72+cc+8] = *(short8*)&tmp[8];
  }
  __syncthreads();
  {
    const int cc=t>>2, rr0=(t&3)*16;
    short tmp[16];
    #pragma unroll
    for(int j=0;j<16;j++) tmp[j]=T[(rr0+j)*72+cc];
    short* o = out + (size_t)(c0+cc)*outRow + r0 + rr0;
    *(short8*)o     = *(short8*)&tmp[0];
    *(short8*)(o+8) = *(short8*)&tmp[8];
  }
}

// Combined prep: blocks 0..1535 transpose-cast x; 1536+ transpose-cast weights.
__global__ __launch_bounds__(256) void prep(const float* __restrict__ x,
                                            const float* __restrict__ Wq, const float* __restrict__ Wk,
                                            const float* __restrict__ Wv, const float* __restrict__ Wo,
                                            short* __restrict__ xb, short* __restrict__ WqT,
                                            short* __restrict__ WkT, short* __restrict__ WvT,
                                            short* __restrict__ WoT){
  __shared__ short T[64*72];
  const int blk=blockIdx.x;
  if(blk<1536){
    const int bx=blk&15, by=(blk>>4)&3, bv=blk>>6;
    tr_tile(x + (size_t)bv*C*HWS, HWS, xb + (size_t)bv*HWS*C, C, by*64, bx*64, T, threadIdx.x);
  } else {
    const int idx=blk-1536;
    const int tile=idx%96, z=idx/96;
    const float* in; short* out; int R;
    if(z==0){in=Wq; out=WqT; R=C;}
    else if(z==1){in=Wo; out=WoT; R=C;}
    else if(z==2){in=Wk; out=WkT; R=VC;}
    else         {in=Wv; out=WvT; R=VC;}
    const int tilesC=C/64, ntiles=(R/64)*tilesC;
    if(tile>=ntiles) return;
    tr_tile(in, C, out, R, (tile/tilesC)*64, (tile%tilesC)*64, T, threadIdx.x);
  }
}

// ---------------------------------------------------------------------------
// qo GEMM body, tile 128x64, BK=64. MODE 0: bf16 out scaled; MODE 1: fp32+res.
// ---------------------------------------------------------------------------
template<int MODE>
__device__ inline void qo_body(const short* __restrict__ A, const short* __restrict__ BT,
                               const float* __restrict__ bias, const float* __restrict__ xres,
                               void* __restrict__ outv, short* As, short* Bs, int n0, int r0){
  const int t=threadIdx.x, lane=t&63, w=t>>6, quad=lane>>4, ln=lane&15;
  f32x4 acc[2][4];
  #pragma unroll
  for(int rt=0;rt<2;rt++)
    #pragma unroll
    for(int nt=0;nt<4;nt++) acc[rt][nt]=(f32x4)0.f;

  for(int k0=0;k0<C;k0+=64){
    if(k0) __syncthreads();
    { const int r=t>>1, c=(t&1)*32;
      const short* p = A + (size_t)(r0+r)*C + k0 + c;
      #pragma unroll
      for(int j=0;j<4;j++) *(short8*)&As[r*72+c+j*8] = *(const short8*)(p+j*8);
    }
    { const int n=t>>2, c=(t&3)*16;
      const short* p = BT + (size_t)(n0+n)*C + k0 + c;
      *(short8*)&Bs[n*72+c]   = *(const short8*)p;
      *(short8*)&Bs[n*72+c+8] = *(const short8*)(p+8);
    }
    __syncthreads();
    #pragma unroll
    for(int s=0;s<2;s++){
      short8 af0=*(short8*)&As[(w*32+ln)*72    + s*32+quad*8];
      short8 af1=*(short8*)&As[(w*32+16+ln)*72 + s*32+quad*8];
      #pragma unroll
      for(int nt=0;nt<4;nt++){
        const short8 bf=*(short8*)&Bs[(nt*16+ln)*72 + s*32+quad*8];
        acc[0][nt]=__builtin_amdgcn_mfma_f32_16x16x32_bf16(af0,bf,acc[0][nt],0,0,0);
        acc[1][nt]=__builtin_amdgcn_mfma_f32_16x16x32_bf16(af1,bf,acc[1][nt],0,0,0);
      }
    }
  }

  constexpr float QSCALE = 0.18033688011112042f;  // 0.125/ln2: softmax via exp2
  float bcol[4];
  #pragma unroll
  for(int nt=0;nt<4;nt++) bcol[nt]=bias[n0+nt*16+ln];
  #pragma unroll
  for(int rt=0;rt<2;rt++)
    #pragma unroll
    for(int nt=0;nt<4;nt++)
      #pragma unroll
      for(int i=0;i<4;i++){
        const int row=r0+w*32+rt*16+quad*4+i, col=n0+nt*16+ln;
        const float vv=acc[rt][nt][i]+bcol[nt];
        if constexpr(MODE==0) ((short*)outv)[(size_t)row*C+col]=f2bf(vv*QSCALE);
        else ((float*)outv)[(size_t)row*C+col]=vv + xres[(size_t)row*C+col];
      }
}

// ---------------------------------------------------------------------------
// Combined projection kernel. Blocks 0..255: fused K+V proj -> Kpack/Vpack.
// Blocks 256..1023: Q projection.
// ---------------------------------------------------------------------------
__global__ __launch_bounds__(256) void proj(const short* __restrict__ xb,
                                            const short* __restrict__ WqT, const short* __restrict__ WkT,
                                            const short* __restrict__ WvT,
                                            const float* __restrict__ bq, const float* __restrict__ bk,
                                            const float* __restrict__ bv,
                                            short* __restrict__ qb, short* __restrict__ Kpack,
                                            short* __restrict__ Vpack){
  __shared__ __align__(16) short sh[13824];
  const int blk=blockIdx.x;
  const int t=threadIdx.x, lane=t&63, w=t>>6, quad=lane>>4, ln=lane&15;

  if(blk>=256){
    const int qblk=blk-256;
    qo_body<0>(xb, WqT, bq, nullptr, qb, sh, sh+9216, (qblk&3)*64, (qblk>>2)*128);
    return;
  }

  // ---- kv path ----
  short* As=sh; short* Bk=sh+4608; short* Bv=sh+9216;
  const int n0=(blk&3)*64, r0=(blk>>2)*64;
  const int b=r0>>10, hw0=r0&1023;
  const int h=n0>>6, bh=b*NH+h;

  f32x4 ak[4], av[4];
  #pragma unroll
  for(int nt=0;nt<4;nt++){ ak[nt]=(f32x4)0.f; av[nt]=(f32x4)0.f; }

  const int sr=t>>2, sc=(t&3)*16;
  for(int k0=0;k0<VC;k0+=64){
    if(k0) __syncthreads();
    const int v=k0>>8, c0=k0&255;
    { const short* p = xb + (size_t)((b*V+v)*HWS + hw0+sr)*C + c0 + sc;
      *(short8*)&As[sr*72+sc]   = *(const short8*)p;
      *(short8*)&As[sr*72+sc+8] = *(const short8*)(p+8); }
    { const short* p = WkT + (size_t)(n0+sr)*VC + k0 + sc;
      *(short8*)&Bk[sr*72+sc]   = *(const short8*)p;
      *(short8*)&Bk[sr*72+sc+8] = *(const short8*)(p+8); }
    { const short* p = WvT + (size_t)(n0+sr)*VC + k0 + sc;
      *(short8*)&Bv[sr*72+sc]   = *(const short8*)p;
      *(short8*)&Bv[sr*72+sc+8] = *(const short8*)(p+8); }
    __syncthreads();
    #pragma unroll
    for(int s=0;s<2;s++){
      const short8 af=*(short8*)&As[(w*16+ln)*72 + s*32+quad*8];
      #pragma unroll
      for(int nt=0;nt<4;nt++){
        const short8 kf=*(short8*)&Bk[(nt*16+ln)*72 + s*32+quad*8];
        const short8 vf=*(short8*)&Bv[(nt*16+ln)*72 + s*32+quad*8];
        ak[nt]=__builtin_amdgcn_mfma_f32_16x16x32_bf16(af,kf,ak[nt],0,0,0);
        av[nt]=__builtin_amdgcn_mfma_f32_16x16x32_bf16(af,vf,av[nt],0,0,0);
      }
    }
  }

  float bkc[4], bvc[4];
  #pragma unroll
  for(int nt=0;nt<4;nt++){ bkc[nt]=bk[n0+nt*16+ln]; bvc[nt]=bv[n0+nt*16+ln]; }

  // V: C-layout (key=quad*4+i, dim=nt*16+ln) IS the PV A-frag mapping.
  {
    short* vq = Vpack + ((size_t)(bh*64 + (hw0>>4) + w))*1024;
    #pragma unroll
    for(int nt=0;nt<4;nt++){
      short4v vp;
      #pragma unroll
      for(int i=0;i<4;i++) vp[i]=f2bf(av[nt][i]+bvc[nt]);
      *(short4v*)(vq + nt*256 + lane*4) = vp;
    }
  }

  // K: transpose C-layout -> A-frag order via LDS (reuse As)
  __syncthreads();
  #pragma unroll
  for(int nt=0;nt<4;nt++)
    #pragma unroll
    for(int i=0;i<4;i++)
      As[(w*16+quad*4+i)*72 + nt*16+ln] = f2bf(ak[nt][i]+bkc[nt]);
  __syncthreads();
  {
    short* kp = Kpack + ((size_t)(bh*64 + (hw0>>4) + w))*1024;
    #pragma unroll
    for(int half=0; half<2; half++){
      const short8 f = *(short8*)&As[(w*16+ln)*72 + half*32 + quad*8];
      *(short8*)(kp + half*512 + lane*8) = f;
    }
  }
}

// ---------------------------------------------------------------------------
// Zero-LDS-main-loop MFMA attention, occupancy-optimized.
// Repartition vs R6: wave = 32 q-rows (wq half) x 32 keys (wk half of each
// 64-key tile). Same MFMA/VALU work per wave, ~half the register state:
// qf 16, o 32 (AGPR), kf 16 transient, no ping-pong (TLP at 4 blk/CU hides
// L2). __launch_bounds__(256,4) pins 4 waves/SIMD.
// ---------------------------------------------------------------------------
__global__ __launch_bounds__(256,4) void attn_k(const short* __restrict__ q, const short* __restrict__ Kpack,
                                                const short* __restrict__ Vpack, short* __restrict__ ao){
  __shared__ float obuf[64*68];   // [dim][qrow]
  __shared__ float lbuf[4][32];
  const int blk=blockIdx.x;
  const int bh=(blk&7)*2 + ((blk>>3)&1);   // XCD-locality swizzle
  const int qt=blk>>4;
  const int b=bh>>2, h=bh&3;
  const int s0=qt*64;
  const int t=threadIdx.x, lane=t&63, w=t>>6, quad=lane>>4, ln=lane&15;
  const int wq=w&1, wk=w>>1;

  // Q B-frags for this wave's 32 q-rows (B[k=dim][n=qrow]: n=ln, k=quad*8+j)
  short8 qf[2][2];
  #pragma unroll
  for(int ntl=0;ntl<2;ntl++)
    #pragma unroll
    for(int s=0;s<2;s++)
      qf[ntl][s]=*(const short8*)&q[(size_t)(b*S+s0+(wq*2+ntl)*16+ln)*C + h*HD + s*32+quad*8];

  f32x4 o[4][2];   // [dt][ntl] of O^T[dim][qrow]
  #pragma unroll
  for(int dt=0;dt<4;dt++)
    #pragma unroll
    for(int ntl=0;ntl<2;ntl++) o[dt][ntl]=(f32x4)0.f;
  f32x4 l4[2];
  l4[0]=(f32x4)0.f; l4[1]=(f32x4)0.f;

  const short* kbase = Kpack + ((size_t)bh*64 + wk*2)*1024;
  const short* vbase = Vpack + ((size_t)bh*64 + wk*2)*1024;
  const f32x4 z4=(f32x4)0.f;
  const int rb = s0 + wq*32;

  #pragma unroll 1
  for(int TI=0; TI<16; TI++){
    const short* kp = kbase + (size_t)TI*4096;
    const short* vp = vbase + (size_t)TI*4096;
    // K A-frags: this wave's 32 keys = 2 x 16-key groups
    const short8 kf00=*(const short8*)(kp + lane*8);
    const short8 kf01=*(const short8*)(kp + 512 + lane*8);
    const short8 kf10=*(const short8*)(kp + 1024 + lane*8);
    const short8 kf11=*(const short8*)(kp + 1536 + lane*8);

    f32x4 sa[2][2];
    #pragma unroll
    for(int ntl=0;ntl<2;ntl++){
      sa[0][ntl]=__builtin_amdgcn_mfma_f32_16x16x32_bf16(kf00,qf[ntl][0],z4,0,0,0);
      sa[0][ntl]=__builtin_amdgcn_mfma_f32_16x16x32_bf16(kf01,qf[ntl][1],sa[0][ntl],0,0,0);
      sa[1][ntl]=__builtin_amdgcn_mfma_f32_16x16x32_bf16(kf10,qf[ntl][0],z4,0,0,0);
      sa[1][ntl]=__builtin_amdgcn_mfma_f32_16x16x32_bf16(kf11,qf[ntl][1],sa[1][ntl],0,0,0);
    }

    // V A-frags issued early; latency hides under mask+exp VALU
    short4v vf[2][4];
    #pragma unroll
    for(int kt=0;kt<2;kt++)
      #pragma unroll
      for(int dt=0;dt<4;dt++)
        vf[kt][dt]=*(const short4v*)(vp + kt*1024 + dt*256 + lane*4);

    // faithful window mask: suppress keys in [ig-3, ig+3]
    const int kmin=TI*64 + wk*32;
    if(kmin+31 >= rb-3 && kmin <= rb+34){
      #pragma unroll
      for(int kt=0;kt<2;kt++)
        #pragma unroll
        for(int ntl=0;ntl<2;ntl++){
          const int ig=rb+ntl*16+ln;
          #pragma unroll
          for(int i=0;i<4;i++){
            const int jg=kmin+kt*16+quad*4+i;
            if((unsigned)(jg-ig+3)<=6u) sa[kt][ntl][i]=-100.f;
          }
        }
    }

    // exp2 + l accumulation + pack P^T (B-frag of 16x16x16)
    short4v pt[2][2];
    #pragma unroll
    for(int kt=0;kt<2;kt++)
      #pragma unroll
      for(int ntl=0;ntl<2;ntl++){
        f32x4 pv;
        #pragma unroll
        for(int i=0;i<4;i++) pv[i]=__builtin_amdgcn_exp2f(sa[kt][ntl][i]);
        l4[ntl]+=pv;
        union{ short4v s; unsigned u[2]; } P;
        P.u[0]=__builtin_amdgcn_perm(fbits(pv[1]), fbits(pv[0]), 0x07060302u);
        P.u[1]=__builtin_amdgcn_perm(fbits(pv[3]), fbits(pv[2]), 0x07060302u);
        pt[kt][ntl]=P.s;
      }

    #pragma unroll
    for(int kt=0;kt<2;kt++)
      #pragma unroll
      for(int dt=0;dt<4;dt++)
        #pragma unroll
        for(int ntl=0;ntl<2;ntl++)
          o[dt][ntl]=__builtin_amdgcn_mfma_f32_16x16x16bf16_1k(vf[kt][dt],pt[kt][ntl],o[dt][ntl],0,0,0);
  }

  // ---- reductions ----
  float l[2];
  #pragma unroll
  for(int ntl=0;ntl<2;ntl++){
    l[ntl]=l4[ntl][0]+l4[ntl][1]+l4[ntl][2]+l4[ntl][3];
    l[ntl]+=__shfl_xor(l[ntl],16);
    l[ntl]+=__shfl_xor(l[ntl],32);
  }
  if(quad==0){
    lbuf[w][ln]    = l[0];
    lbuf[w][16+ln] = l[1];
  }
  // O: 2 accumulation rounds (wk halves); wq halves write disjoint columns
  if(wk==0){
    #pragma unroll
    for(int dt=0;dt<4;dt++)
      #pragma unroll
      for(int ntl=0;ntl<2;ntl++)
        #pragma unroll
        for(int i=0;i<4;i++)
          obuf[(dt*16+quad*4+i)*68 + wq*32+ntl*16+ln] = o[dt][ntl][i];
  }
  __syncthreads();
  if(wk==1){
    #pragma unroll
    for(int dt=0;dt<4;dt++)
      #pragma unroll
      for(int ntl=0;ntl<2;ntl++)
        #pragma unroll
        for(int i=0;i<4;i++)
          obuf[(dt*16+quad*4+i)*68 + wq*32+ntl*16+ln] += o[dt][ntl][i];
  }
  __syncthreads();

  {
    const int row=t>>2, dg=t&3;
    const int wqr=row>>5, idx=row&31;
    const float linv=1.0f/(lbuf[wqr][idx]+lbuf[wqr+2][idx]);
    short tmp[16];
    #pragma unroll
    for(int j=0;j<16;j++) tmp[j]=f2bf(obuf[(dg*16+j)*68+row]*linv);
    short* op = ao + (size_t)(b*S+s0+row)*C + h*HD + dg*16;
    *(short8*)op     = *(short8*)&tmp[0];
    *(short8*)(op+8) = *(short8*)&tmp[8];
  }
}

// O-projection + residual (MODE 1 wrapper)
__global__ __launch_bounds__(256) void o_gemm(const short* __restrict__ A, const short* __restrict__ BT,
                                              const float* __restrict__ bias, const float* __restrict__ xres,
                                              float* __restrict__ out){
  __shared__ __align__(16) short sh[13824];
  qo_body<1>(A, BT, bias, xres, out, sh, sh+9216, (int)(blockIdx.x&3)*64, (int)(blockIdx.x>>2)*128);
}

}  // namespace

extern "C" void kernel_launch(void* const* d_in, const int* in_sizes, int n_in,
                              void* d_out, int out_size, void* d_ws, size_t ws_size,
                              hipStream_t stream) {
  const float* x  = (const float*)d_in[0];
  const float* Wq = (const float*)d_in[1];
  const float* bq = (const float*)d_in[2];
  const float* Wk = (const float*)d_in[3];
  const float* bk = (const float*)d_in[4];
  const float* Wv = (const float*)d_in[5];
  const float* bv = (const float*)d_in[6];
  const float* Wo = (const float*)d_in[7];
  const float* bo = (const float*)d_in[8];
  float* out = (float*)d_out;

  char* p = (char*)d_ws;
  const size_t szBS=(size_t)B*S*C*2, szK=(size_t)B*HWS*C*2;
  short* xb   =(short*)p; p+=szBS;
  short* qb   =(short*)p; p+=szBS;
  short* aob  =(short*)p; p+=szBS;
  short* Kpack=(short*)p; p+=szK;
  short* Vpack=(short*)p; p+=szK;
  short* WqT=(short*)p; p+=(size_t)C*C*2;
  short* WoT=(short*)p; p+=(size_t)C*C*2;
  short* WkT=(short*)p; p+=(size_t)C*VC*2;
  short* WvT=(short*)p; p+=(size_t)C*VC*2;

  prep<<<dim3(1920), 256, 0, stream>>>(x, Wq,Wk,Wv,Wo, xb, WqT,WkT,WvT,WoT);
  proj<<<dim3(1024), 256, 0, stream>>>(xb, WqT,WkT,WvT, bq,bk,bv, qb, Kpack, Vpack);
  attn_k<<<dim3(B*NH*(S/64)), 256, 0, stream>>>(qb, Kpack, Vpack, aob);
  o_gemm<<<dim3(4*((B*S)/128)), 256, 0, stream>>>(aob, WoT, bo, x, out);
}

// Round 8
// 184.311 us; speedup vs baseline: 1.2941x; 1.0321x over previous
//
#include <hip/hip_runtime.h>
#include <cstddef>

namespace {

constexpr int B=4, V=6, C=256, HWS=1024, S=6144, NH=4, HD=64, VC=1536;

typedef short short8  __attribute__((ext_vector_type(8)));
typedef short short4v __attribute__((ext_vector_type(4)));
typedef float f32x4   __attribute__((ext_vector_type(4)));

__device__ inline short f2bf(float f){
  union{float f; unsigned u;} v; v.f=f;
  unsigned r = v.u + 0x7fffu + ((v.u>>16)&1u);   // RNE
  return (short)(r>>16);
}
__device__ inline unsigned fbits(float f){
  union{float f; unsigned u;} v; v.f=f; return v.u;
}

// async global->LDS, 16B per lane; LDS dest = wave-uniform base + lane*16
typedef const __attribute__((address_space(1))) unsigned* gas_t;
typedef __attribute__((address_space(3))) unsigned* las_t;
__device__ inline void gll(const void* g, void* l){
  __builtin_amdgcn_global_load_lds((gas_t)g, (las_t)l, 16, 0, 0);
}

// ---------------------------------------------------------------------------
// 64x64 transpose-cast tile, register 4x4 micro-transpose (no LDS).
// Reads coalesced float4; writes b64 (4x 32B strips per 16-lane group — full
// line utilization across the block's 4 waves).
// ---------------------------------------------------------------------------
__device__ inline void tr_tile(const float* in, int inRow, short* out, int outRow,
                               int r0, int c0, int t){
  const int tx=t&15, ty=t>>4;
  float a[4][4];
  #pragma unroll
  for(int i=0;i<4;i++){
    const float4 f=*(const float4*)(in + (size_t)(r0+ty*4+i)*inRow + c0 + tx*4);
    a[i][0]=f.x; a[i][1]=f.y; a[i][2]=f.z; a[i][3]=f.w;
  }
  #pragma unroll
  for(int j=0;j<4;j++){
    short4v o4;
    #pragma unroll
    for(int i=0;i<4;i++) o4[i]=f2bf(a[i][j]);
    *(short4v*)(out + (size_t)(c0+tx*4+j)*outRow + r0+ty*4) = o4;
  }
}

// Combined prep: blocks 0..1535 transpose-cast x; 1536+ transpose-cast weights.
__global__ __launch_bounds__(256) void prep(const float* __restrict__ x,
                                            const float* __restrict__ Wq, const float* __restrict__ Wk,
                                            const float* __restrict__ Wv, const float* __restrict__ Wo,
                                            short* __restrict__ xb, short* __restrict__ WqT,
                                            short* __restrict__ WkT, short* __restrict__ WvT,
                                            short* __restrict__ WoT){
  const int blk=blockIdx.x;
  if(blk<1536){
    const int bx=blk&15, by=(blk>>4)&3, bv=blk>>6;
    tr_tile(x + (size_t)bv*C*HWS, HWS, xb + (size_t)bv*HWS*C, C, by*64, bx*64, threadIdx.x);
  } else {
    const int idx=blk-1536;
    const int tile=idx%96, z=idx/96;
    const float* in; short* out; int R;
    if(z==0){in=Wq; out=WqT; R=C;}
    else if(z==1){in=Wo; out=WoT; R=C;}
    else if(z==2){in=Wk; out=WkT; R=VC;}
    else         {in=Wv; out=WvT; R=VC;}
    const int tilesC=C/64, ntiles=(R/64)*tilesC;
    if(tile>=ntiles) return;
    tr_tile(in, C, out, R, (tile/tilesC)*64, (tile%tilesC)*64, threadIdx.x);
  }
}

// ---------------------------------------------------------------------------
// qo GEMM body, tile 128x64, BK=64. MODE 0: bf16 out scaled; MODE 1: fp32+res.
// ---------------------------------------------------------------------------
template<int MODE>
__device__ inline void qo_body(const short* __restrict__ A, const short* __restrict__ BT,
                               const float* __restrict__ bias, const float* __restrict__ xres,
                               void* __restrict__ outv, short* As, short* Bs, int n0, int r0){
  const int t=threadIdx.x, lane=t&63, w=t>>6, quad=lane>>4, ln=lane&15;
  f32x4 acc[2][4];
  #pragma unroll
  for(int rt=0;rt<2;rt++)
    #pragma unroll
    for(int nt=0;nt<4;nt++) acc[rt][nt]=(f32x4)0.f;

  for(int k0=0;k0<C;k0+=64){
    if(k0) __syncthreads();
    { const int r=t>>1, c=(t&1)*32;
      const short* p = A + (size_t)(r0+r)*C + k0 + c;
      #pragma unroll
      for(int j=0;j<4;j++) *(short8*)&As[r*72+c+j*8] = *(const short8*)(p+j*8);
    }
    { const int n=t>>2, c=(t&3)*16;
      const short* p = BT + (size_t)(n0+n)*C + k0 + c;
      *(short8*)&Bs[n*72+c]   = *(const short8*)p;
      *(short8*)&Bs[n*72+c+8] = *(const short8*)(p+8);
    }
    __syncthreads();
    #pragma unroll
    for(int s=0;s<2;s++){
      short8 af0=*(short8*)&As[(w*32+ln)*72    + s*32+quad*8];
      short8 af1=*(short8*)&As[(w*32+16+ln)*72 + s*32+quad*8];
      #pragma unroll
      for(int nt=0;nt<4;nt++){
        const short8 bf=*(short8*)&Bs[(nt*16+ln)*72 + s*32+quad*8];
        acc[0][nt]=__builtin_amdgcn_mfma_f32_16x16x32_bf16(af0,bf,acc[0][nt],0,0,0);
        acc[1][nt]=__builtin_amdgcn_mfma_f32_16x16x32_bf16(af1,bf,acc[1][nt],0,0,0);
      }
    }
  }

  constexpr float QSCALE = 0.18033688011112042f;  // 0.125/ln2: softmax via exp2
  float bcol[4];
  #pragma unroll
  for(int nt=0;nt<4;nt++) bcol[nt]=bias[n0+nt*16+ln];
  #pragma unroll
  for(int rt=0;rt<2;rt++)
    #pragma unroll
    for(int nt=0;nt<4;nt++)
      #pragma unroll
      for(int i=0;i<4;i++){
        const int row=r0+w*32+rt*16+quad*4+i, col=n0+nt*16+ln;
        const float vv=acc[rt][nt][i]+bcol[nt];
        if constexpr(MODE==0) ((short*)outv)[(size_t)row*C+col]=f2bf(vv*QSCALE);
        else ((float*)outv)[(size_t)row*C+col]=vv + xres[(size_t)row*C+col];
      }
}

// ---------------------------------------------------------------------------
// Combined projection kernel. Blocks 0..255: fused K+V proj -> Kpack/Vpack.
// Blocks 256..1023: Q projection.
// ---------------------------------------------------------------------------
__global__ __launch_bounds__(256) void proj(const short* __restrict__ xb,
                                            const short* __restrict__ WqT, const short* __restrict__ WkT,
                                            const short* __restrict__ WvT,
                                            const float* __restrict__ bq, const float* __restrict__ bk,
                                            const float* __restrict__ bv,
                                            short* __restrict__ qb, short* __restrict__ Kpack,
                                            short* __restrict__ Vpack){
  __shared__ __align__(16) short sh[13824];
  const int blk=blockIdx.x;
  const int t=threadIdx.x, lane=t&63, w=t>>6, quad=lane>>4, ln=lane&15;

  if(blk>=256){
    const int qblk=blk-256;
    qo_body<0>(xb, WqT, bq, nullptr, qb, sh, sh+9216, (qblk&3)*64, (qblk>>2)*128);
    return;
  }

  // ---- kv path ----
  short* As=sh; short* Bk=sh+4608; short* Bv=sh+9216;
  const int n0=(blk&3)*64, r0=(blk>>2)*64;
  const int b=r0>>10, hw0=r0&1023;
  const int h=n0>>6, bh=b*NH+h;

  f32x4 ak[4], av[4];
  #pragma unroll
  for(int nt=0;nt<4;nt++){ ak[nt]=(f32x4)0.f; av[nt]=(f32x4)0.f; }

  const int sr=t>>2, sc=(t&3)*16;
  for(int k0=0;k0<VC;k0+=64){
    if(k0) __syncthreads();
    const int v=k0>>8, c0=k0&255;
    { const short* p = xb + (size_t)((b*V+v)*HWS + hw0+sr)*C + c0 + sc;
      *(short8*)&As[sr*72+sc]   = *(const short8*)p;
      *(short8*)&As[sr*72+sc+8] = *(const short8*)(p+8); }
    { const short* p = WkT + (size_t)(n0+sr)*VC + k0 + sc;
      *(short8*)&Bk[sr*72+sc]   = *(const short8*)p;
      *(short8*)&Bk[sr*72+sc+8] = *(const short8*)(p+8); }
    { const short* p = WvT + (size_t)(n0+sr)*VC + k0 + sc;
      *(short8*)&Bv[sr*72+sc]   = *(const short8*)p;
      *(short8*)&Bv[sr*72+sc+8] = *(const short8*)(p+8); }
    __syncthreads();
    #pragma unroll
    for(int s=0;s<2;s++){
      const short8 af=*(short8*)&As[(w*16+ln)*72 + s*32+quad*8];
      #pragma unroll
      for(int nt=0;nt<4;nt++){
        const short8 kf=*(short8*)&Bk[(nt*16+ln)*72 + s*32+quad*8];
        const short8 vf=*(short8*)&Bv[(nt*16+ln)*72 + s*32+quad*8];
        ak[nt]=__builtin_amdgcn_mfma_f32_16x16x32_bf16(af,kf,ak[nt],0,0,0);
        av[nt]=__builtin_amdgcn_mfma_f32_16x16x32_bf16(af,vf,av[nt],0,0,0);
      }
    }
  }

  float bkc[4], bvc[4];
  #pragma unroll
  for(int nt=0;nt<4;nt++){ bkc[nt]=bk[n0+nt*16+ln]; bvc[nt]=bv[n0+nt*16+ln]; }

  // V: C-layout (key=quad*4+i, dim=nt*16+ln) IS the PV A-frag mapping.
  {
    short* vq = Vpack + ((size_t)(bh*64 + (hw0>>4) + w))*1024;
    #pragma unroll
    for(int nt=0;nt<4;nt++){
      short4v vp;
      #pragma unroll
      for(int i=0;i<4;i++) vp[i]=f2bf(av[nt][i]+bvc[nt]);
      *(short4v*)(vq + nt*256 + lane*4) = vp;
    }
  }

  // K: transpose C-layout -> A-frag order via LDS (reuse As)
  __syncthreads();
  #pragma unroll
  for(int nt=0;nt<4;nt++)
    #pragma unroll
    for(int i=0;i<4;i++)
      As[(w*16+quad*4+i)*72 + nt*16+ln] = f2bf(ak[nt][i]+bkc[nt]);
  __syncthreads();
  {
    short* kp = Kpack + ((size_t)(bh*64 + (hw0>>4) + w))*1024;
    #pragma unroll
    for(int half=0; half<2; half++){
      const short8 f = *(short8*)&As[(w*16+ln)*72 + half*32 + quad*8];
      *(short8*)(kp + half*512 + lane*8) = f;
    }
  }
}

// ---------------------------------------------------------------------------
// MFMA attention: LDS-staged fragment-packed K/V (double-buffered via
// global_load_lds), 512 threads, 128 q-rows/block.
// Wave = 32 q-rows (wq=w&3) x 32 keys (wk=w>>2) of each 64-key tile.
// K/V tile staged ONCE per block (no per-wave L2 duplication); frag reads
// from LDS are contiguous b128/b64 (conflict-free). One barrier per tile.
// obuf overlays the K/V buffers after the loop.
// ---------------------------------------------------------------------------
__global__ __launch_bounds__(512,4) void attn_k(const short* __restrict__ q, const short* __restrict__ Kpack,
                                                const short* __restrict__ Vpack, short* __restrict__ ao){
  __shared__ __align__(16) char smem[34816];
  short* KV   = (short*)smem;                 // 2 bufs x (K 4096 | V 4096) shorts
  float* obuf = (float*)smem;                 // overlay: 64 dims x pitch 132
  float* lbuf = (float*)(smem + 33792);       // 8 x 32 floats

  const int blk=blockIdx.x;
  const int bh=(blk&7)*2 + ((blk>>3)&1);      // XCD-locality swizzle
  const int qt=blk>>4;                        // 0..47
  const int b=bh>>2, h=bh&3;
  const int s0=qt*128;
  const int t=threadIdx.x, lane=t&63, w=t>>6, quad=lane>>4, ln=lane&15;
  const int wq=w&3, wk=w>>2;

  // Q B-frags for this wave's 32 q-rows (B[k=dim][n=qrow]: n=ln, k=quad*8+j)
  short8 qf[2][2];
  #pragma unroll
  for(int ntl=0;ntl<2;ntl++)
    #pragma unroll
    for(int s=0;s<2;s++)
      qf[ntl][s]=*(const short8*)&q[(size_t)(b*S+s0+wq*32+ntl*16+ln)*C + h*HD + s*32+quad*8];

  f32x4 o[4][2];
  #pragma unroll
  for(int dt=0;dt<4;dt++)
    #pragma unroll
    for(int ntl=0;ntl<2;ntl++) o[dt][ntl]=(f32x4)0.f;
  f32x4 l4[2];
  l4[0]=(f32x4)0.f; l4[1]=(f32x4)0.f;

  const short* Kt = Kpack + (size_t)bh*65536;
  const short* Vt = Vpack + (size_t)bh*65536;
  const f32x4 z4=(f32x4)0.f;
  const int rb = s0 + wq*32;

  // stage tile 0
  gll(Kt + w*512 + lane*8, KV + w*512);
  gll(Vt + 0*4096 + w*512 + lane*8, KV + 4096 + w*512);
  __syncthreads();

  #pragma unroll 1
  for(int TI=0; TI<16; TI++){
    if(TI<15){
      const int nb=(TI+1)&1;
      gll(Kt + (size_t)(TI+1)*4096 + w*512 + lane*8, KV + nb*8192 + w*512);
      gll(Vt + (size_t)(TI+1)*4096 + w*512 + lane*8, KV + nb*8192 + 4096 + w*512);
    }
    const short* Kb = KV + (TI&1)*8192;
    const short* Vb = Kb + 4096;

    const short8 kf00=*(const short8*)&Kb[wk*2048 + lane*8];
    const short8 kf01=*(const short8*)&Kb[wk*2048 + 512 + lane*8];
    const short8 kf10=*(const short8*)&Kb[wk*2048 + 1024 + lane*8];
    const short8 kf11=*(const short8*)&Kb[wk*2048 + 1536 + lane*8];

    f32x4 sa[2][2];
    #pragma unroll
    for(int ntl=0;ntl<2;ntl++){
      sa[0][ntl]=__builtin_amdgcn_mfma_f32_16x16x32_bf16(kf00,qf[ntl][0],z4,0,0,0);
      sa[0][ntl]=__builtin_amdgcn_mfma_f32_16x16x32_bf16(kf01,qf[ntl][1],sa[0][ntl],0,0,0);
      sa[1][ntl]=__builtin_amdgcn_mfma_f32_16x16x32_bf16(kf10,qf[ntl][0],z4,0,0,0);
      sa[1][ntl]=__builtin_amdgcn_mfma_f32_16x16x32_bf16(kf11,qf[ntl][1],sa[1][ntl],0,0,0);
    }

    short4v vf[2][4];
    #pragma unroll
    for(int kt=0;kt<2;kt++)
      #pragma unroll
      for(int dt=0;dt<4;dt++)
        vf[kt][dt]=*(const short4v*)&Vb[wk*2048 + kt*1024 + dt*256 + lane*4];

    // faithful window mask: suppress keys in [ig-3, ig+3]
    const int kmin=TI*64 + wk*32;
    if(kmin+31 >= rb-3 && kmin <= rb+34){
      #pragma unroll
      for(int kt=0;kt<2;kt++)
        #pragma unroll
        for(int ntl=0;ntl<2;ntl++){
          const int ig=rb+ntl*16+ln;
          #pragma unroll
          for(int i=0;i<4;i++){
            const int jg=kmin+kt*16+quad*4+i;
            if((unsigned)(jg-ig+3)<=6u) sa[kt][ntl][i]=-100.f;
          }
        }
    }

    // exp2 + l accumulation + pack P^T (B-frag of 16x16x16)
    short4v pt[2][2];
    #pragma unroll
    for(int kt=0;kt<2;kt++)
      #pragma unroll
      for(int ntl=0;ntl<2;ntl++){
        f32x4 pv;
        #pragma unroll
        for(int i=0;i<4;i++) pv[i]=__builtin_amdgcn_exp2f(sa[kt][ntl][i]);
        l4[ntl]+=pv;
        union{ short4v s; unsigned u[2]; } P;
        P.u[0]=__builtin_amdgcn_perm(fbits(pv[1]), fbits(pv[0]), 0x07060302u);
        P.u[1]=__builtin_amdgcn_perm(fbits(pv[3]), fbits(pv[2]), 0x07060302u);
        pt[kt][ntl]=P.s;
      }

    #pragma unroll
    for(int kt=0;kt<2;kt++)
      #pragma unroll
      for(int dt=0;dt<4;dt++)
        #pragma unroll
        for(int ntl=0;ntl<2;ntl++)
          o[dt][ntl]=__builtin_amdgcn_mfma_f32_16x16x16bf16_1k(vf[kt][dt],pt[kt][ntl],o[dt][ntl],0,0,0);

    __syncthreads();   // buf[TI] consumed by all; staging of TI+1 drained
  }

  // ---- reductions (obuf overlays KV; all waves past final barrier) ----
  float l[2];
  #pragma unroll
  for(int ntl=0;ntl<2;ntl++){
    l[ntl]=l4[ntl][0]+l4[ntl][1]+l4[ntl][2]+l4[ntl][3];
    l[ntl]+=__shfl_xor(l[ntl],16);
    l[ntl]+=__shfl_xor(l[ntl],32);
  }
  if(quad==0){
    lbuf[w*32+ln]    = l[0];
    lbuf[w*32+16+ln] = l[1];
  }
  if(wk==0){
    #pragma unroll
    for(int dt=0;dt<4;dt++)
      #pragma unroll
      for(int ntl=0;ntl<2;ntl++)
        #pragma unroll
        for(int i=0;i<4;i++)
          obuf[(dt*16+quad*4+i)*132 + wq*32+ntl*16+ln] = o[dt][ntl][i];
  }
  __syncthreads();
  if(wk==1){
    #pragma unroll
    for(int dt=0;dt<4;dt++)
      #pragma unroll
      for(int ntl=0;ntl<2;ntl++)
        #pragma unroll
        for(int i=0;i<4;i++)
          obuf[(dt*16+quad*4+i)*132 + wq*32+ntl*16+ln] += o[dt][ntl][i];
  }
  __syncthreads();

  {
    const int row=t>>2, dg=t&3;
    const float linv=1.0f/(lbuf[(row>>5)*32 + (row&31)] + lbuf[(4+(row>>5))*32 + (row&31)]);
    short tmp[16];
    #pragma unroll
    for(int j=0;j<16;j++) tmp[j]=f2bf(obuf[(dg*16+j)*132+row]*linv);
    short* op = ao + (size_t)(b*S+s0+row)*C + h*HD + dg*16;
    *(short8*)op     = *(short8*)&tmp[0];
    *(short8*)(op+8) = *(short8*)&tmp[8];
  }
}

// O-projection + residual (MODE 1 wrapper)
__global__ __launch_bounds__(256) void o_gemm(const short* __restrict__ A, const short* __restrict__ BT,
                                              const float* __restrict__ bias, const float* __restrict__ xres,
                                              float* __restrict__ out){
  __shared__ __align__(16) short sh[13824];
  qo_body<1>(A, BT, bias, xres, out, sh, sh+9216, (int)(blockIdx.x&3)*64, (int)(blockIdx.x>>2)*128);
}

}  // namespace

extern "C" void kernel_launch(void* const* d_in, const int* in_sizes, int n_in,
                              void* d_out, int out_size, void* d_ws, size_t ws_size,
                              hipStream_t stream) {
  const float* x  = (const float*)d_in[0];
  const float* Wq = (const float*)d_in[1];
  const float* bq = (const float*)d_in[2];
  const float* Wk = (const float*)d_in[3];
  const float* bk = (const float*)d_in[4];
  const float* Wv = (const float*)d_in[5];
  const float* bv = (const float*)d_in[6];
  const float* Wo = (const float*)d_in[7];
  const float* bo = (const float*)d_in[8];
  float* out = (float*)d_out;

  char* p = (char*)d_ws;
  const size_t szBS=(size_t)B*S*C*2, szK=(size_t)B*HWS*C*2;
  short* xb   =(short*)p; p+=szBS;
  short* qb   =(short*)p; p+=szBS;
  short* aob  =(short*)p; p+=szBS;
  short* Kpack=(short*)p; p+=szK;
  short* Vpack=(short*)p; p+=szK;
  short* WqT=(short*)p; p+=(size_t)C*C*2;
  short* WoT=(short*)p; p+=(size_t)C*C*2;
  short* WkT=(short*)p; p+=(size_t)C*VC*2;
  short* WvT=(short*)p; p+=(size_t)C*VC*2;

  prep<<<dim3(1920), 256, 0, stream>>>(x, Wq,Wk,Wv,Wo, xb, WqT,WkT,WvT,WoT);
  proj<<<dim3(1024), 256, 0, stream>>>(xb, WqT,WkT,WvT, bq,bk,bv, qb, Kpack, Vpack);
  attn_k<<<dim3(B*NH*(S/128)), 512, 0, stream>>>(qb, Kpack, Vpack, aob);
  o_gemm<<<dim3(4*((B*S)/128)), 256, 0, stream>>>(aob, WoT, bo, x, out);
}

// Round 9
// 169.762 us; speedup vs baseline: 1.4050x; 1.0857x over previous
//
#include <hip/hip_runtime.h>
#include <cstddef>

namespace {

constexpr int B=4, V=6, C=256, HWS=1024, S=6144, NH=4, HD=64, VC=1536;

typedef short short8  __attribute__((ext_vector_type(8)));
typedef short short4v __attribute__((ext_vector_type(4)));
typedef float f32x4   __attribute__((ext_vector_type(4)));

__device__ inline short f2bf(float f){
  union{float f; unsigned u;} v; v.f=f;
  unsigned r = v.u + 0x7fffu + ((v.u>>16)&1u);   // RNE
  return (short)(r>>16);
}
__device__ inline unsigned fbits(float f){
  union{float f; unsigned u;} v; v.f=f; return v.u;
}

// async global->LDS, 16B per lane; LDS dest = wave-uniform base, HW adds lane*16
typedef const __attribute__((address_space(1))) unsigned* gas_t;
typedef __attribute__((address_space(3))) unsigned* las_t;
__device__ inline void gll(const void* g, void* l){
  __builtin_amdgcn_global_load_lds((gas_t)g, (las_t)l, 16, 0, 0);
}

// ---------------------------------------------------------------------------
// 64x64 transpose-cast tile, register 4x4 micro-transpose (no LDS).
// ---------------------------------------------------------------------------
__device__ inline void tr_tile(const float* in, int inRow, short* out, int outRow,
                               int r0, int c0, int t){
  const int tx=t&15, ty=t>>4;
  float a[4][4];
  #pragma unroll
  for(int i=0;i<4;i++){
    const float4 f=*(const float4*)(in + (size_t)(r0+ty*4+i)*inRow + c0 + tx*4);
    a[i][0]=f.x; a[i][1]=f.y; a[i][2]=f.z; a[i][3]=f.w;
  }
  #pragma unroll
  for(int j=0;j<4;j++){
    short4v o4;
    #pragma unroll
    for(int i=0;i<4;i++) o4[i]=f2bf(a[i][j]);
    *(short4v*)(out + (size_t)(c0+tx*4+j)*outRow + r0+ty*4) = o4;
  }
}

// Combined prep: blocks 0..1535 transpose-cast x; 1536+ transpose-cast weights.
__global__ __launch_bounds__(256) void prep(const float* __restrict__ x,
                                            const float* __restrict__ Wq, const float* __restrict__ Wk,
                                            const float* __restrict__ Wv, const float* __restrict__ Wo,
                                            short* __restrict__ xb, short* __restrict__ WqT,
                                            short* __restrict__ WkT, short* __restrict__ WvT,
                                            short* __restrict__ WoT){
  const int blk=blockIdx.x;
  if(blk<1536){
    const int bx=blk&15, by=(blk>>4)&3, bv=blk>>6;
    tr_tile(x + (size_t)bv*C*HWS, HWS, xb + (size_t)bv*HWS*C, C, by*64, bx*64, threadIdx.x);
  } else {
    const int idx=blk-1536;
    const int tile=idx%96, z=idx/96;
    const float* in; short* out; int R;
    if(z==0){in=Wq; out=WqT; R=C;}
    else if(z==1){in=Wo; out=WoT; R=C;}
    else if(z==2){in=Wk; out=WkT; R=VC;}
    else         {in=Wv; out=WvT; R=VC;}
    const int tilesC=C/64, ntiles=(R/64)*tilesC;
    if(tile>=ntiles) return;
    tr_tile(in, C, out, R, (tile/tilesC)*64, (tile%tilesC)*64, threadIdx.x);
  }
}

// ---------------------------------------------------------------------------
// qo GEMM body, tile 128x64, BK=64, m97-style: gll staging, double-buffered
// LDS (2 x (A 16KB + B 8KB)), one barrier/iter, next-tile gll issued before
// compute. Tiles pitch-64 (gll order). MODE 0: bf16*QSCALE; MODE 1: fp32+res.
// ---------------------------------------------------------------------------
template<int MODE>
__device__ inline void qo_body(const short* __restrict__ A, const short* __restrict__ BT,
                               const float* __restrict__ bias, const float* __restrict__ xres,
                               void* __restrict__ outv, short* sh, int n0, int r0){
  const int t=threadIdx.x, lane=t&63, w=t>>6, quad=lane>>4, ln=lane&15;
  f32x4 acc[2][4];
  #pragma unroll
  for(int rt=0;rt<2;rt++)
    #pragma unroll
    for(int nt=0;nt<4;nt++) acc[rt][nt]=(f32x4)0.f;

  const int sr=w*8+(lane>>3), scc=(lane&7)*8;
  auto stage=[&](int it,int bufi){
    const int k0=it*64;
    short* dst = sh + bufi*12288;
    const short* Asrc = A + (size_t)r0*C + k0;
    #pragma unroll
    for(int cc=0; cc<4; cc++)
      gll(Asrc + (size_t)(sr+cc*32)*C + scc, dst + cc*2048 + w*512);
    const short* Bsrc = BT + (size_t)n0*C + k0;
    gll(Bsrc + (size_t)sr*C + scc,      dst + 8192 + w*512);
    gll(Bsrc + (size_t)(sr+32)*C + scc, dst + 8192 + 2048 + w*512);
  };

  stage(0,0);
  __syncthreads();
  for(int it=0; it<4; it++){
    if(it<3) stage(it+1,(it+1)&1);
    const short* As_=sh+(it&1)*12288;
    const short* Bs_=As_+8192;
    #pragma unroll
    for(int s=0;s<2;s++){
      const short8 af0=*(const short8*)&As_[(w*32+ln)*64    + s*32+quad*8];
      const short8 af1=*(const short8*)&As_[(w*32+16+ln)*64 + s*32+quad*8];
      #pragma unroll
      for(int nt=0;nt<4;nt++){
        const short8 bf=*(const short8*)&Bs_[(nt*16+ln)*64 + s*32+quad*8];
        acc[0][nt]=__builtin_amdgcn_mfma_f32_16x16x32_bf16(af0,bf,acc[0][nt],0,0,0);
        acc[1][nt]=__builtin_amdgcn_mfma_f32_16x16x32_bf16(af1,bf,acc[1][nt],0,0,0);
      }
    }
    __syncthreads();
  }

  constexpr float QSCALE = 0.18033688011112042f;  // 0.125/ln2: softmax via exp2
  float bcol[4];
  #pragma unroll
  for(int nt=0;nt<4;nt++) bcol[nt]=bias[n0+nt*16+ln];
  #pragma unroll
  for(int rt=0;rt<2;rt++)
    #pragma unroll
    for(int nt=0;nt<4;nt++)
      #pragma unroll
      for(int i=0;i<4;i++){
        const int row=r0+w*32+rt*16+quad*4+i, col=n0+nt*16+ln;
        const float vv=acc[rt][nt][i]+bcol[nt];
        if constexpr(MODE==0) ((short*)outv)[(size_t)row*C+col]=f2bf(vv*QSCALE);
        else ((float*)outv)[(size_t)row*C+col]=vv + xres[(size_t)row*C+col];
      }
}

// ---------------------------------------------------------------------------
// Combined projection kernel. Blocks 0..255: fused K+V proj (m97-style gll
// double-buffered staging of A/Bk/Bv) -> fragment-packed Kpack/Vpack.
// Blocks 256..1023: Q projection via qo_body.
// ---------------------------------------------------------------------------
__global__ __launch_bounds__(256) void proj(const short* __restrict__ xb,
                                            const short* __restrict__ WqT, const short* __restrict__ WkT,
                                            const short* __restrict__ WvT,
                                            const float* __restrict__ bq, const float* __restrict__ bk,
                                            const float* __restrict__ bv,
                                            short* __restrict__ qb, short* __restrict__ Kpack,
                                            short* __restrict__ Vpack){
  __shared__ __align__(16) short sh[24576];   // 48 KB: 2 bufs x 3 x 64x64
  const int blk=blockIdx.x;
  const int t=threadIdx.x, lane=t&63, w=t>>6, quad=lane>>4, ln=lane&15;

  if(blk>=256){
    const int qblk=blk-256;
    qo_body<0>(xb, WqT, bq, nullptr, qb, sh, (qblk&3)*64, (qblk>>2)*128);
    return;
  }

  // ---- kv path ----
  const int n0=(blk&3)*64, r0=(blk>>2)*64;
  const int b=r0>>10, hw0=r0&1023;
  const int h=n0>>6, bh=b*NH+h;

  f32x4 ak[4], av[4];
  #pragma unroll
  for(int nt=0;nt<4;nt++){ ak[nt]=(f32x4)0.f; av[nt]=(f32x4)0.f; }

  const int sr=w*8+(lane>>3), scc=(lane&7)*8;
  auto stageKV=[&](int it,int bufi){
    const int k0=it*64, v=k0>>8, c0=k0&255;
    short* dst = sh + bufi*12288;
    const short* As_src = xb + (size_t)((b*V+v)*HWS + hw0)*C + c0;
    gll(As_src + (size_t)sr*C + scc,       dst + w*512);
    gll(As_src + (size_t)(sr+32)*C + scc,  dst + 2048 + w*512);
    const short* Bk_src = WkT + (size_t)n0*VC + k0;
    gll(Bk_src + (size_t)sr*VC + scc,      dst + 4096 + w*512);
    gll(Bk_src + (size_t)(sr+32)*VC + scc, dst + 4096 + 2048 + w*512);
    const short* Bv_src = WvT + (size_t)n0*VC + k0;
    gll(Bv_src + (size_t)sr*VC + scc,      dst + 8192 + w*512);
    gll(Bv_src + (size_t)(sr+32)*VC + scc, dst + 8192 + 2048 + w*512);
  };

  stageKV(0,0);
  __syncthreads();
  for(int it=0; it<24; it++){
    if(it<23) stageKV(it+1,(it+1)&1);
    const short* As_=sh+(it&1)*12288;
    const short* Bk_=As_+4096;
    const short* Bv_=As_+8192;
    #pragma unroll
    for(int s=0;s<2;s++){
      const short8 af=*(const short8*)&As_[(w*16+ln)*64 + s*32+quad*8];
      #pragma unroll
      for(int nt=0;nt<4;nt++){
        const short8 kf=*(const short8*)&Bk_[(nt*16+ln)*64 + s*32+quad*8];
        const short8 vf=*(const short8*)&Bv_[(nt*16+ln)*64 + s*32+quad*8];
        ak[nt]=__builtin_amdgcn_mfma_f32_16x16x32_bf16(af,kf,ak[nt],0,0,0);
        av[nt]=__builtin_amdgcn_mfma_f32_16x16x32_bf16(af,vf,av[nt],0,0,0);
      }
    }
    __syncthreads();
  }

  float bkc[4], bvc[4];
  #pragma unroll
  for(int nt=0;nt<4;nt++){ bkc[nt]=bk[n0+nt*16+ln]; bvc[nt]=bv[n0+nt*16+ln]; }

  // V: C-layout (key=quad*4+i, dim=nt*16+ln) IS the PV A-frag mapping.
  {
    short* vq = Vpack + ((size_t)(bh*64 + (hw0>>4) + w))*1024;
    #pragma unroll
    for(int nt=0;nt<4;nt++){
      short4v vp;
      #pragma unroll
      for(int i=0;i<4;i++) vp[i]=f2bf(av[nt][i]+bvc[nt]);
      *(short4v*)(vq + nt*256 + lane*4) = vp;
    }
  }

  // K: transpose C-layout -> A-frag order via LDS (reuse sh, pitch 72)
  __syncthreads();
  #pragma unroll
  for(int nt=0;nt<4;nt++)
    #pragma unroll
    for(int i=0;i<4;i++)
      sh[(w*16+quad*4+i)*72 + nt*16+ln] = f2bf(ak[nt][i]+bkc[nt]);
  __syncthreads();
  {
    short* kp = Kpack + ((size_t)(bh*64 + (hw0>>4) + w))*1024;
    #pragma unroll
    for(int half=0; half<2; half++){
      const short8 f = *(short8*)&sh[(w*16+ln)*72 + half*32 + quad*8];
      *(short8*)(kp + half*512 + lane*8) = f;
    }
  }
}

// ---------------------------------------------------------------------------
// MFMA attention (unchanged from R8): LDS-staged fragment-packed K/V
// (double-buffered gll), 512 threads, 128 q-rows/block.
// ---------------------------------------------------------------------------
__global__ __launch_bounds__(512,4) void attn_k(const short* __restrict__ q, const short* __restrict__ Kpack,
                                                const short* __restrict__ Vpack, short* __restrict__ ao){
  __shared__ __align__(16) char smem[34816];
  short* KV   = (short*)smem;
  float* obuf = (float*)smem;                 // overlay: 64 dims x pitch 132
  float* lbuf = (float*)(smem + 33792);

  const int blk=blockIdx.x;
  const int bh=(blk&7)*2 + ((blk>>3)&1);
  const int qt=blk>>4;
  const int b=bh>>2, h=bh&3;
  const int s0=qt*128;
  const int t=threadIdx.x, lane=t&63, w=t>>6, quad=lane>>4, ln=lane&15;
  const int wq=w&3, wk=w>>2;

  short8 qf[2][2];
  #pragma unroll
  for(int ntl=0;ntl<2;ntl++)
    #pragma unroll
    for(int s=0;s<2;s++)
      qf[ntl][s]=*(const short8*)&q[(size_t)(b*S+s0+wq*32+ntl*16+ln)*C + h*HD + s*32+quad*8];

  f32x4 o[4][2];
  #pragma unroll
  for(int dt=0;dt<4;dt++)
    #pragma unroll
    for(int ntl=0;ntl<2;ntl++) o[dt][ntl]=(f32x4)0.f;
  f32x4 l4[2];
  l4[0]=(f32x4)0.f; l4[1]=(f32x4)0.f;

  const short* Kt = Kpack + (size_t)bh*65536;
  const short* Vt = Vpack + (size_t)bh*65536;
  const f32x4 z4=(f32x4)0.f;
  const int rb = s0 + wq*32;

  gll(Kt + w*512 + lane*8, KV + w*512);
  gll(Vt + w*512 + lane*8, KV + 4096 + w*512);
  __syncthreads();

  #pragma unroll 1
  for(int TI=0; TI<16; TI++){
    if(TI<15){
      const int nb=(TI+1)&1;
      gll(Kt + (size_t)(TI+1)*4096 + w*512 + lane*8, KV + nb*8192 + w*512);
      gll(Vt + (size_t)(TI+1)*4096 + w*512 + lane*8, KV + nb*8192 + 4096 + w*512);
    }
    const short* Kb = KV + (TI&1)*8192;
    const short* Vb = Kb + 4096;

    const short8 kf00=*(const short8*)&Kb[wk*2048 + lane*8];
    const short8 kf01=*(const short8*)&Kb[wk*2048 + 512 + lane*8];
    const short8 kf10=*(const short8*)&Kb[wk*2048 + 1024 + lane*8];
    const short8 kf11=*(const short8*)&Kb[wk*2048 + 1536 + lane*8];

    f32x4 sa[2][2];
    #pragma unroll
    for(int ntl=0;ntl<2;ntl++){
      sa[0][ntl]=__builtin_amdgcn_mfma_f32_16x16x32_bf16(kf00,qf[ntl][0],z4,0,0,0);
      sa[0][ntl]=__builtin_amdgcn_mfma_f32_16x16x32_bf16(kf01,qf[ntl][1],sa[0][ntl],0,0,0);
      sa[1][ntl]=__builtin_amdgcn_mfma_f32_16x16x32_bf16(kf10,qf[ntl][0],z4,0,0,0);
      sa[1][ntl]=__builtin_amdgcn_mfma_f32_16x16x32_bf16(kf11,qf[ntl][1],sa[1][ntl],0,0,0);
    }

    short4v vf[2][4];
    #pragma unroll
    for(int kt=0;kt<2;kt++)
      #pragma unroll
      for(int dt=0;dt<4;dt++)
        vf[kt][dt]=*(const short4v*)&Vb[wk*2048 + kt*1024 + dt*256 + lane*4];

    const int kmin=TI*64 + wk*32;
    if(kmin+31 >= rb-3 && kmin <= rb+34){
      #pragma unroll
      for(int kt=0;kt<2;kt++)
        #pragma unroll
        for(int ntl=0;ntl<2;ntl++){
          const int ig=rb+ntl*16+ln;
          #pragma unroll
          for(int i=0;i<4;i++){
            const int jg=kmin+kt*16+quad*4+i;
            if((unsigned)(jg-ig+3)<=6u) sa[kt][ntl][i]=-100.f;
          }
        }
    }

    short4v pt[2][2];
    #pragma unroll
    for(int kt=0;kt<2;kt++)
      #pragma unroll
      for(int ntl=0;ntl<2;ntl++){
        f32x4 pv;
        #pragma unroll
        for(int i=0;i<4;i++) pv[i]=__builtin_amdgcn_exp2f(sa[kt][ntl][i]);
        l4[ntl]+=pv;
        union{ short4v s; unsigned u[2]; } P;
        P.u[0]=__builtin_amdgcn_perm(fbits(pv[1]), fbits(pv[0]), 0x07060302u);
        P.u[1]=__builtin_amdgcn_perm(fbits(pv[3]), fbits(pv[2]), 0x07060302u);
        pt[kt][ntl]=P.s;
      }

    #pragma unroll
    for(int kt=0;kt<2;kt++)
      #pragma unroll
      for(int dt=0;dt<4;dt++)
        #pragma unroll
        for(int ntl=0;ntl<2;ntl++)
          o[dt][ntl]=__builtin_amdgcn_mfma_f32_16x16x16bf16_1k(vf[kt][dt],pt[kt][ntl],o[dt][ntl],0,0,0);

    __syncthreads();
  }

  float l[2];
  #pragma unroll
  for(int ntl=0;ntl<2;ntl++){
    l[ntl]=l4[ntl][0]+l4[ntl][1]+l4[ntl][2]+l4[ntl][3];
    l[ntl]+=__shfl_xor(l[ntl],16);
    l[ntl]+=__shfl_xor(l[ntl],32);
  }
  if(quad==0){
    lbuf[w*32+ln]    = l[0];
    lbuf[w*32+16+ln] = l[1];
  }
  if(wk==0){
    #pragma unroll
    for(int dt=0;dt<4;dt++)
      #pragma unroll
      for(int ntl=0;ntl<2;ntl++)
        #pragma unroll
        for(int i=0;i<4;i++)
          obuf[(dt*16+quad*4+i)*132 + wq*32+ntl*16+ln] = o[dt][ntl][i];
  }
  __syncthreads();
  if(wk==1){
    #pragma unroll
    for(int dt=0;dt<4;dt++)
      #pragma unroll
      for(int ntl=0;ntl<2;ntl++)
        #pragma unroll
        for(int i=0;i<4;i++)
          obuf[(dt*16+quad*4+i)*132 + wq*32+ntl*16+ln] += o[dt][ntl][i];
  }
  __syncthreads();

  {
    const int row=t>>2, dg=t&3;
    const float linv=1.0f/(lbuf[(row>>5)*32 + (row&31)] + lbuf[(4+(row>>5))*32 + (row&31)]);
    short tmp[16];
    #pragma unroll
    for(int j=0;j<16;j++) tmp[j]=f2bf(obuf[(dg*16+j)*132+row]*linv);
    short* op = ao + (size_t)(b*S+s0+row)*C + h*HD + dg*16;
    *(short8*)op     = *(short8*)&tmp[0];
    *(short8*)(op+8) = *(short8*)&tmp[8];
  }
}

// O-projection + residual (MODE 1 wrapper)
__global__ __launch_bounds__(256) void o_gemm(const short* __restrict__ A, const short* __restrict__ BT,
                                              const float* __restrict__ bias, const float* __restrict__ xres,
                                              float* __restrict__ out){
  __shared__ __align__(16) short sh[24576];
  qo_body<1>(A, BT, bias, xres, out, sh, (int)(blockIdx.x&3)*64, (int)(blockIdx.x>>2)*128);
}

}  // namespace

extern "C" void kernel_launch(void* const* d_in, const int* in_sizes, int n_in,
                              void* d_out, int out_size, void* d_ws, size_t ws_size,
                              hipStream_t stream) {
  const float* x  = (const float*)d_in[0];
  const float* Wq = (const float*)d_in[1];
  const float* bq = (const float*)d_in[2];
  const float* Wk = (const float*)d_in[3];
  const float* bk = (const float*)d_in[4];
  const float* Wv = (const float*)d_in[5];
  const float* bv = (const float*)d_in[6];
  const float* Wo = (const float*)d_in[7];
  const float* bo = (const float*)d_in[8];
  float* out = (float*)d_out;

  char* p = (char*)d_ws;
  const size_t szBS=(size_t)B*S*C*2, szK=(size_t)B*HWS*C*2;
  short* xb   =(short*)p; p+=szBS;
  short* qb   =(short*)p; p+=szBS;
  short* aob  =(short*)p; p+=szBS;
  short* Kpack=(short*)p; p+=szK;
  short* Vpack=(short*)p; p+=szK;
  short* WqT=(short*)p; p+=(size_t)C*C*2;
  short* WoT=(short*)p; p+=(size_t)C*C*2;
  short* WkT=(short*)p; p+=(size_t)C*VC*2;
  short* WvT=(short*)p; p+=(size_t)C*VC*2;

  prep<<<dim3(1920), 256, 0, stream>>>(x, Wq,Wk,Wv,Wo, xb, WqT,WkT,WvT,WoT);
  proj<<<dim3(1024), 256, 0, stream>>>(xb, WqT,WkT,WvT, bq,bk,bv, qb, Kpack, Vpack);
  attn_k<<<dim3(B*NH*(S/128)), 512, 0, stream>>>(qb, Kpack, Vpack, aob);
  o_gemm<<<dim3(4*((B*S)/128)), 256, 0, stream>>>(aob, WoT, bo, x, out);
}